// Round 1
// 4729.041 us; speedup vs baseline: 2.5923x; 2.5923x over previous
//
#include <hip/hip_runtime.h>
#include <hip/hip_bf16.h>

// Problem constants (BinaryClassifyModel: L=6, B=8, S=2048, H=768, V=32000)
// All model inputs are float32 (per reference); internal activations bf16.
#define Bn 8
#define Sn 2048
#define Hn 768
#define FFn 3072
#define Ln 6
#define BSn (Bn * Sn)       // 16384 tokens
#define CQ 512              // query chunk for attention scores buffer
#define LN_EPS 1e-5f

typedef __hip_bfloat16 bf16;
typedef __bf16 bf16x8 __attribute__((ext_vector_type(8)));
typedef float f32x4 __attribute__((ext_vector_type(4)));

__device__ __forceinline__ float b2f(bf16 v) { return __bfloat162float(v); }
__device__ __forceinline__ void stc(float* p, float v) { *p = v; }
__device__ __forceinline__ void stc(bf16* p, float v) { *p = __float2bfloat16(v); }

union Pk8 { float4 v; bf16 h[8]; };   // 8 consecutive bf16 = one 16B load

// async global->LDS, 16B per lane; LDS dest = wave-uniform base + lane*16
__device__ __forceinline__ void gld16(const bf16* g, short* l) {
  __builtin_amdgcn_global_load_lds(
      (const __attribute__((address_space(1))) unsigned int*)g,
      (__attribute__((address_space(3))) unsigned int*)l, 16, 0, 0);
}

// ---------------------------------------------------------------------------
// Embedding: x[b,s,:] = tok_emb[ids[b,s],:] + pos_emb[s,:]   (f32 in, f32 out)
// ---------------------------------------------------------------------------
__global__ void __launch_bounds__(256) embed_kernel(
    const int* __restrict__ ids, const float* __restrict__ tok,
    const float* __restrict__ pos, float* __restrict__ x) {
  long t = blockIdx.x;
  int s = (int)(t & (Sn - 1));
  long id = ids[t];
  const float* tr = tok + id * Hn;
  const float* pr = pos + (long)s * Hn;
  float* xr = x + t * Hn;
  for (int d = threadIdx.x; d < Hn; d += 256)
    xr[d] = tr[d] + pr[d];
}

// ---------------------------------------------------------------------------
// Weight transpose + cast: Wt[n][k] = (bf16)W[k][n].  W: [K][N] f32.
// 32x32 tile, 256 threads (32x8), both sides coalesced.
// ---------------------------------------------------------------------------
__global__ void __launch_bounds__(256) transpose_cvt_kernel(
    const float* __restrict__ W, bf16* __restrict__ Wt, int K, int N) {
  __shared__ float t[32][33];
  int n0 = blockIdx.x * 32, k0 = blockIdx.y * 32;
  int tx = threadIdx.x & 31, ty = threadIdx.x >> 5;  // ty 0..7
#pragma unroll
  for (int i = 0; i < 32; i += 8)
    t[ty + i][tx] = W[(long)(k0 + ty + i) * N + n0 + tx];
  __syncthreads();
#pragma unroll
  for (int i = 0; i < 32; i += 8)
    stc(Wt + (long)(n0 + ty + i) * K + k0 + tx, t[tx][ty + i]);
}

// ---------------------------------------------------------------------------
// LayerNorm: one 256-thread block per token. x: f32 in, out: bf16
// ---------------------------------------------------------------------------
__global__ void __launch_bounds__(256) ln_kernel(
    const float* __restrict__ x, const float* __restrict__ g,
    const float* __restrict__ b, bf16* __restrict__ out) {
  long token = blockIdx.x;
  const float* xr = x + token * Hn;
  bf16* orow = out + token * Hn;
  int tid = threadIdx.x;

  float vals[3];
  float s1 = 0.f;
#pragma unroll
  for (int i = 0; i < 3; i++) {
    vals[i] = xr[tid + 256 * i];
    s1 += vals[i];
  }
  __shared__ float sb[4];
  __shared__ float stat[2];
#pragma unroll
  for (int off = 32; off > 0; off >>= 1) s1 += __shfl_down(s1, off, 64);
  if ((tid & 63) == 0) sb[tid >> 6] = s1;
  __syncthreads();
  if (tid == 0) stat[0] = (sb[0] + sb[1] + sb[2] + sb[3]) * (1.0f / Hn);
  __syncthreads();
  float mean = stat[0];

  float s2 = 0.f;
#pragma unroll
  for (int i = 0; i < 3; i++) {
    float d = vals[i] - mean;
    s2 += d * d;
  }
#pragma unroll
  for (int off = 32; off > 0; off >>= 1) s2 += __shfl_down(s2, off, 64);
  if ((tid & 63) == 0) sb[tid >> 6] = s2;
  __syncthreads();
  if (tid == 0)
    stat[1] = rsqrtf((sb[0] + sb[1] + sb[2] + sb[3]) * (1.0f / Hn) + LN_EPS);
  __syncthreads();
  float inv = stat[1];

#pragma unroll
  for (int i = 0; i < 3; i++) {
    int d = tid + 256 * i;
    stc(orow + d, (vals[i] - mean) * inv * g[d] + b[d]);
  }
}

// ---------------------------------------------------------------------------
// MFMA GEMM: C[M,N] = epilogue(A[M,K] @ Bt[N,K]^T + bias[N] (+ res[M,N]))
//   A: bf16 row-major [M][K];  Bt: bf16 row-major [N][K] (= B^T);
//   bias: f32; res: f32; C: bf16 or f32.
//   EPI: 0 = bias, 1 = bias + residual, 2 = gelu(bias),
//        3 = bias + store V^T: C treated as vT[Bn][Hn][Sn], row=token -> (b,s)
//   128x128 tile, BK=32, 4 waves (each 64x64 = 4x4 mfma_16x16x32 tiles).
//   Staging: global_load_lds 16B/lane; frags: ds_read_b128.
//   M%128==0, N%128==0, K%32==0 assumed.
// ---------------------------------------------------------------------------
template <int EPI, typename CT>
__global__ void __launch_bounds__(256) mfma_gemm_kernel(
    const bf16* __restrict__ A, const bf16* __restrict__ Bt,
    const float* __restrict__ bias, const float* __restrict__ res,
    CT* __restrict__ C, int M, int N, int K) {
  __shared__ short As[128 * 32];   // [row][k] rows of 64B
  __shared__ short Bs[128 * 32];   // [col][k]
  int tid = threadIdx.x;
  int wave = tid >> 6, lane = tid & 63;
  int waveM = wave >> 1, waveN = wave & 1;
  int quad = lane >> 4, l16 = lane & 15;
  long rowBase = (long)blockIdx.y * 128;
  long colBase = (long)blockIdx.x * 128;
  const bf16* Ag = A + rowBase * K;
  const bf16* Bg = Bt + colBase * K;

  int srow = lane >> 2;           // 0..15 staging row within 16-row chunk
  int schunk = (lane & 3) * 8;    // 0,8,16,24 (k elements)

  f32x4 acc[4][4] = {};

  for (int kt = 0; kt < K; kt += 32) {
    // each wave stages 32 rows of A and 32 rows of B (2 x 16-row chunks)
#pragma unroll
    for (int c = 0; c < 2; c++) {
      int r0 = wave * 32 + c * 16;
      gld16(Ag + (long)(r0 + srow) * K + kt + schunk, &As[r0 * 32]);
      gld16(Bg + (long)(r0 + srow) * K + kt + schunk, &Bs[r0 * 32]);
    }
    __syncthreads();

    bf16x8 af[4], bfr[4];
#pragma unroll
    for (int t = 0; t < 4; t++)
      af[t] = *(const bf16x8*)&As[(waveM * 64 + t * 16 + l16) * 32 + quad * 8];
#pragma unroll
    for (int u = 0; u < 4; u++)
      bfr[u] = *(const bf16x8*)&Bs[(waveN * 64 + u * 16 + l16) * 32 + quad * 8];
#pragma unroll
    for (int t = 0; t < 4; t++)
#pragma unroll
      for (int u = 0; u < 4; u++)
        acc[t][u] = __builtin_amdgcn_mfma_f32_16x16x32_bf16(af[t], bfr[u],
                                                            acc[t][u], 0, 0, 0);
    __syncthreads();
  }

  // epilogue: D col=lane&15, row=quad*4+reg  [verified mapping]
#pragma unroll
  for (int t = 0; t < 4; t++) {
#pragma unroll
    for (int u = 0; u < 4; u++) {
      int col = (int)colBase + waveN * 64 + u * 16 + l16;
      float bv = bias[col];
      if (EPI == 3) {
        // transposed store: 4 consecutive token rows -> 4 consecutive s
        union { uint2 w; bf16 h[4]; } pk;
        long row0 = rowBase + waveM * 64 + t * 16 + quad * 4;
        long bb = row0 >> 11;          // token / Sn
        long s = row0 & (Sn - 1);      // token % Sn (block spans one batch)
#pragma unroll
        for (int r = 0; r < 4; r++)
          pk.h[r] = __float2bfloat16(acc[t][u][r] + bv);
        *reinterpret_cast<uint2*>((bf16*)C + (bb * Hn + col) * Sn + s) = pk.w;
      } else {
#pragma unroll
        for (int r = 0; r < 4; r++) {
          long row = rowBase + waveM * 64 + t * 16 + quad * 4 + r;
          float v = acc[t][u][r] + bv;
          if (EPI == 1) v += res[row * N + col];
          if (EPI == 2) v = 0.5f * v * (1.0f + erff(v * 0.70710678118654752f));
          stc(C + row * N + col, v);
        }
      }
    }
  }
}

// ---------------------------------------------------------------------------
// QK^T via MFMA: sc[b, qRel, k] = scale * dot(Q[b,q,:], K[b,k,:])
//   Q,K: [B][S][H] bf16 row-major; K rows are the natural Bt operand.
//   128x128 tile; causal early-out for fully masked tiles.
// ---------------------------------------------------------------------------
__global__ void __launch_bounds__(256) qk_mfma_kernel(
    const bf16* __restrict__ q, const bf16* __restrict__ k,
    bf16* __restrict__ sc, int q0) {
  int kBase = blockIdx.x * 128;
  int qBase = q0 + blockIdx.y * 128;   // absolute q
  if (kBase > qBase + 127) return;     // fully masked tile
  int b = blockIdx.z;
  const bf16* Ag = q + ((long)b * Sn + qBase) * Hn;
  const bf16* Bg = k + ((long)b * Sn + kBase) * Hn;

  __shared__ short As[128 * 32];
  __shared__ short Bs[128 * 32];
  int tid = threadIdx.x;
  int wave = tid >> 6, lane = tid & 63;
  int waveM = wave >> 1, waveN = wave & 1;
  int quad = lane >> 4, l16 = lane & 15;
  int srow = lane >> 2;
  int schunk = (lane & 3) * 8;

  f32x4 acc[4][4] = {};

  for (int kt = 0; kt < Hn; kt += 32) {
#pragma unroll
    for (int c = 0; c < 2; c++) {
      int r0 = wave * 32 + c * 16;
      gld16(Ag + (long)(r0 + srow) * Hn + kt + schunk, &As[r0 * 32]);
      gld16(Bg + (long)(r0 + srow) * Hn + kt + schunk, &Bs[r0 * 32]);
    }
    __syncthreads();

    bf16x8 af[4], bfr[4];
#pragma unroll
    for (int t = 0; t < 4; t++)
      af[t] = *(const bf16x8*)&As[(waveM * 64 + t * 16 + l16) * 32 + quad * 8];
#pragma unroll
    for (int u = 0; u < 4; u++)
      bfr[u] = *(const bf16x8*)&Bs[(waveN * 64 + u * 16 + l16) * 32 + quad * 8];
#pragma unroll
    for (int t = 0; t < 4; t++)
#pragma unroll
      for (int u = 0; u < 4; u++)
        acc[t][u] = __builtin_amdgcn_mfma_f32_16x16x32_bf16(af[t], bfr[u],
                                                            acc[t][u], 0, 0, 0);
    __syncthreads();
  }

  const float scale = 0.03608439182435161f;  // 1/sqrt(768)
#pragma unroll
  for (int t = 0; t < 4; t++)
#pragma unroll
    for (int u = 0; u < 4; u++) {
      int col = kBase + waveN * 64 + u * 16 + l16;
#pragma unroll
      for (int r = 0; r < 4; r++) {
        long qRel = (long)(qBase - q0) + waveM * 64 + t * 16 + quad * 4 + r;
        stc(sc + ((long)b * CQ + qRel) * Sn + col, acc[t][u][r] * scale);
      }
    }
}

// ---------------------------------------------------------------------------
// P @ V via MFMA: o[b,q,:] = P[b,qRel,:klimit] @ V[b,:klimit,:]
//   P: [B][CQ][Sn] bf16 (probs, zero-filled to 128-aligned limit);
//   vT: [B][Hn][Sn] bf16 (= V^T, written by EPI=3 GEMM) — natural Bt operand.
//   Causal: K-loop only to klimit = qBase+128.
// ---------------------------------------------------------------------------
__global__ void __launch_bounds__(256) pv_mfma_kernel(
    const bf16* __restrict__ p, const bf16* __restrict__ vT,
    bf16* __restrict__ o, int q0) {
  int colBase = blockIdx.x * 128;      // over Hn
  int qBase = q0 + blockIdx.y * 128;   // absolute q
  int b = blockIdx.z;
  int klimit = qBase + 128;            // multiple of 128
  const bf16* Ag = p + ((long)b * CQ + (qBase - q0)) * Sn;
  const bf16* Bg = vT + ((long)b * Hn + colBase) * Sn;

  __shared__ short As[128 * 32];
  __shared__ short Bs[128 * 32];
  int tid = threadIdx.x;
  int wave = tid >> 6, lane = tid & 63;
  int waveM = wave >> 1, waveN = wave & 1;
  int quad = lane >> 4, l16 = lane & 15;
  int srow = lane >> 2;
  int schunk = (lane & 3) * 8;

  f32x4 acc[4][4] = {};

  for (int kt = 0; kt < klimit; kt += 32) {
#pragma unroll
    for (int c = 0; c < 2; c++) {
      int r0 = wave * 32 + c * 16;
      gld16(Ag + (long)(r0 + srow) * Sn + kt + schunk, &As[r0 * 32]);
      gld16(Bg + (long)(r0 + srow) * Sn + kt + schunk, &Bs[r0 * 32]);
    }
    __syncthreads();

    bf16x8 af[4], bfr[4];
#pragma unroll
    for (int t = 0; t < 4; t++)
      af[t] = *(const bf16x8*)&As[(waveM * 64 + t * 16 + l16) * 32 + quad * 8];
#pragma unroll
    for (int u = 0; u < 4; u++)
      bfr[u] = *(const bf16x8*)&Bs[(waveN * 64 + u * 16 + l16) * 32 + quad * 8];
#pragma unroll
    for (int t = 0; t < 4; t++)
#pragma unroll
      for (int u = 0; u < 4; u++)
        acc[t][u] = __builtin_amdgcn_mfma_f32_16x16x32_bf16(af[t], bfr[u],
                                                            acc[t][u], 0, 0, 0);
    __syncthreads();
  }

#pragma unroll
  for (int t = 0; t < 4; t++)
#pragma unroll
    for (int u = 0; u < 4; u++) {
      int col = colBase + waveN * 64 + u * 16 + l16;
#pragma unroll
      for (int r = 0; r < 4; r++) {
        long qAbs = (long)qBase + waveM * 64 + t * 16 + quad * 4 + r;
        stc(o + ((long)b * Sn + qAbs) * Hn + col, acc[t][u][r]);
      }
    }
}

// ---------------------------------------------------------------------------
// Softmax over one score row (block per (qRel, b)).
// Zero-fills [n, limit) with limit 128-aligned so PV's 128-wide K tiles
// never read stale garbage.
// ---------------------------------------------------------------------------
__global__ void __launch_bounds__(256) softmax_kernel(
    bf16* __restrict__ sc, const int* __restrict__ mask, int q0) {
  int qRel = blockIdx.x;
  int b = blockIdx.y;
  int qg = q0 + qRel;
  bf16* row = sc + ((long)b * CQ + qRel) * Sn;
  const int* mrow = mask + b * Sn;
  int tid = threadIdx.x;
  int n = qg + 1;
  int limit = (qg & ~127) + 128;

  float sv[8];
  float lmax = -1e30f;
#pragma unroll
  for (int it = 0; it < 8; it++) {
    int kk = tid + it * 256;
    float s = -1e30f;
    if (kk < n) {
      s = b2f(row[kk]);
      if (mrow[kk] == 0) s = -1e30f;
    }
    sv[it] = s;
    lmax = fmaxf(lmax, s);
  }
  __shared__ float sb[4];
  __shared__ float stat;
#pragma unroll
  for (int off = 32; off > 0; off >>= 1)
    lmax = fmaxf(lmax, __shfl_down(lmax, off, 64));
  if ((tid & 63) == 0) sb[tid >> 6] = lmax;
  __syncthreads();
  if (tid == 0) stat = fmaxf(fmaxf(sb[0], sb[1]), fmaxf(sb[2], sb[3]));
  __syncthreads();
  float gmax = stat;

  float ev[8];
  float lsum = 0.f;
#pragma unroll
  for (int it = 0; it < 8; it++) {
    int kk = tid + it * 256;
    float e = 0.f;
    if (kk < n) e = __expf(sv[it] - gmax);
    ev[it] = e;
    lsum += e;
  }
#pragma unroll
  for (int off = 32; off > 0; off >>= 1) lsum += __shfl_down(lsum, off, 64);
  if ((tid & 63) == 0) sb[tid >> 6] = lsum;
  __syncthreads();
  if (tid == 0) stat = sb[0] + sb[1] + sb[2] + sb[3];
  __syncthreads();
  float inv = 1.0f / stat;

#pragma unroll
  for (int it = 0; it < 8; it++) {
    int kk = tid + it * 256;
    if (kk < n)
      stc(row + kk, ev[it] * inv);
    else if (kk < limit)
      stc(row + kk, 0.f);
  }
}

// ---------------------------------------------------------------------------
// Classifier head
// ---------------------------------------------------------------------------
__global__ void __launch_bounds__(256) cls_kernel(
    const bf16* __restrict__ h, const int* __restrict__ mask,
    const float* __restrict__ clsW, const float* __restrict__ clsb,
    float* __restrict__ out) {
  int b = blockIdx.x;
  int tid = threadIdx.x;
  __shared__ float sb[4];
  __shared__ int ib[4];
  __shared__ int lastsh;

  int ls = 0;
  for (int s = tid; s < Sn; s += 256) ls += mask[b * Sn + s];
#pragma unroll
  for (int off = 32; off > 0; off >>= 1) ls += __shfl_down(ls, off, 64);
  if ((tid & 63) == 0) ib[tid >> 6] = ls;
  __syncthreads();
  if (tid == 0) lastsh = ib[0] + ib[1] + ib[2] + ib[3] - 1;
  __syncthreads();
  int last = lastsh;

  const bf16* row = h + ((long)b * Sn + last) * Hn;
  float acc = 0.f;
  for (int d = tid; d < Hn; d += 256) acc += b2f(row[d]) * clsW[d];
#pragma unroll
  for (int off = 32; off > 0; off >>= 1) acc += __shfl_down(acc, off, 64);
  if ((tid & 63) == 0) sb[tid >> 6] = acc;
  __syncthreads();
  if (tid == 0) out[b] = sb[0] + sb[1] + sb[2] + sb[3] + clsb[0];
}

// ---------------------------------------------------------------------------
// Orchestration
// ---------------------------------------------------------------------------
extern "C" void kernel_launch(void* const* d_in, const int* in_sizes, int n_in,
                              void* d_out, int out_size, void* d_ws,
                              size_t ws_size, hipStream_t stream) {
  const int* ids     = (const int*)d_in[0];
  const int* mask    = (const int*)d_in[1];
  const float* tok   = (const float*)d_in[2];
  const float* pos   = (const float*)d_in[3];
  const float* Wq    = (const float*)d_in[4];
  const float* bq    = (const float*)d_in[5];
  const float* Wk    = (const float*)d_in[6];
  const float* bk    = (const float*)d_in[7];
  const float* Wv    = (const float*)d_in[8];
  const float* bv    = (const float*)d_in[9];
  const float* Wo    = (const float*)d_in[10];
  const float* bo    = (const float*)d_in[11];
  const float* ln1g  = (const float*)d_in[12];
  const float* ln1b  = (const float*)d_in[13];
  const float* ln2g  = (const float*)d_in[14];
  const float* ln2b  = (const float*)d_in[15];
  const float* W1    = (const float*)d_in[16];
  const float* b1    = (const float*)d_in[17];
  const float* W2    = (const float*)d_in[18];
  const float* b2    = (const float*)d_in[19];
  const float* flng  = (const float*)d_in[20];
  const float* flnb  = (const float*)d_in[21];
  const float* clsW  = (const float*)d_in[22];
  const float* clsb  = (const float*)d_in[23];

  // Workspace layout (~190 MB):
  //   x  : BS*H f32   (persistent hidden state)         50.3 MB
  //   h  : BS*H bf16  (LN output / attention output)    25.2 MB
  //   cb : BS*FF bf16 (q,k,vT + scores chunk; FFN mid) 100.7 MB
  //   wt : per-layer transposed bf16 weights            14.2 MB
  float* x = (float*)d_ws;
  bf16* h  = (bf16*)(x + (size_t)BSn * Hn);
  bf16* cb = h + (size_t)BSn * Hn;
  bf16* qb = cb;
  bf16* kb = cb + (size_t)BSn * Hn;
  bf16* vtb = cb + 2 * (size_t)BSn * Hn;  // V^T [Bn][Hn][Sn] (same size as vb)
  bf16* scb = cb + 3 * (size_t)BSn * Hn;  // [Bn, CQ, Sn] bf16 = 16.8 MB
  bf16* wt = cb + (size_t)BSn * FFn;
  bf16* wqT = wt;                                   // [H][H]
  bf16* wkT = wqT + (size_t)Hn * Hn;
  bf16* wvT = wkT + (size_t)Hn * Hn;
  bf16* woT = wvT + (size_t)Hn * Hn;
  bf16* w1T = woT + (size_t)Hn * Hn;                // [FF][H]
  bf16* w2T = w1T + (size_t)Hn * FFn;               // [H][FF]

  const int M = BSn;
  dim3 blk(256);
  dim3 gridH128(Hn / 128, M / 128);   // N=768
  dim3 gridF128(FFn / 128, M / 128);  // N=3072
  dim3 gridQK(Sn / 128, CQ / 128, Bn);
  dim3 gridSM(CQ, Bn);
  dim3 gridPV(Hn / 128, CQ / 128, Bn);
  dim3 gridTH(Hn / 32, Hn / 32);      // transpose H x H
  dim3 gridT1(FFn / 32, Hn / 32);     // W1: K=H, N=FF
  dim3 gridT2(Hn / 32, FFn / 32);     // W2: K=FF, N=H

  embed_kernel<<<BSn, blk, 0, stream>>>(ids, tok, pos, x);

  for (int l = 0; l < Ln; l++) {
    const float* Wq_l = Wq + (size_t)l * Hn * Hn;
    const float* Wk_l = Wk + (size_t)l * Hn * Hn;
    const float* Wv_l = Wv + (size_t)l * Hn * Hn;
    const float* Wo_l = Wo + (size_t)l * Hn * Hn;
    const float* W1_l = W1 + (size_t)l * Hn * FFn;
    const float* W2_l = W2 + (size_t)l * FFn * Hn;

    // per-layer weight transpose+cast into wt (reused each layer)
    transpose_cvt_kernel<<<gridTH, blk, 0, stream>>>(Wq_l, wqT, Hn, Hn);
    transpose_cvt_kernel<<<gridTH, blk, 0, stream>>>(Wk_l, wkT, Hn, Hn);
    transpose_cvt_kernel<<<gridTH, blk, 0, stream>>>(Wv_l, wvT, Hn, Hn);
    transpose_cvt_kernel<<<gridTH, blk, 0, stream>>>(Wo_l, woT, Hn, Hn);
    transpose_cvt_kernel<<<gridT1, blk, 0, stream>>>(W1_l, w1T, Hn, FFn);
    transpose_cvt_kernel<<<gridT2, blk, 0, stream>>>(W2_l, w2T, FFn, Hn);

    // --- attention block ---
    ln_kernel<<<BSn, blk, 0, stream>>>(x, ln1g + l * Hn, ln1b + l * Hn, h);
    mfma_gemm_kernel<0, bf16><<<gridH128, blk, 0, stream>>>(
        h, wqT, bq + l * Hn, nullptr, qb, M, Hn, Hn);
    mfma_gemm_kernel<0, bf16><<<gridH128, blk, 0, stream>>>(
        h, wkT, bk + l * Hn, nullptr, kb, M, Hn, Hn);
    // V projection stores V^T directly (EPI=3)
    mfma_gemm_kernel<3, bf16><<<gridH128, blk, 0, stream>>>(
        h, wvT, bv + l * Hn, nullptr, vtb, M, Hn, Hn);
    for (int c = 0; c < Sn / CQ; c++) {
      int q0 = c * CQ;
      qk_mfma_kernel<<<gridQK, blk, 0, stream>>>(qb, kb, scb, q0);
      softmax_kernel<<<gridSM, blk, 0, stream>>>(scb, mask, q0);
      pv_mfma_kernel<<<gridPV, blk, 0, stream>>>(scb, vtb, h, q0);
    }
    mfma_gemm_kernel<1, float><<<gridH128, blk, 0, stream>>>(
        h, woT, bo + l * Hn, x, x, M, Hn, Hn);

    // --- FFN block ---
    ln_kernel<<<BSn, blk, 0, stream>>>(x, ln2g + l * Hn, ln2b + l * Hn, h);
    mfma_gemm_kernel<2, bf16><<<gridF128, blk, 0, stream>>>(
        h, w1T, b1 + l * FFn, nullptr, cb, M, FFn, Hn);
    mfma_gemm_kernel<1, float><<<gridH128, blk, 0, stream>>>(
        cb, w2T, b2 + l * Hn, x, x, M, Hn, FFn);
  }

  ln_kernel<<<BSn, blk, 0, stream>>>(x, flng, flnb, h);
  cls_kernel<<<Bn, blk, 0, stream>>>(h, mask, clsW, clsb, (float*)d_out);
}

// Round 2
// 4438.911 us; speedup vs baseline: 2.7617x; 1.0654x over previous
//
#include <hip/hip_runtime.h>
#include <hip/hip_bf16.h>

// Problem constants (BinaryClassifyModel: L=6, B=8, S=2048, H=768, V=32000)
// All model inputs are float32 (per reference); internal activations bf16.
#define Bn 8
#define Sn 2048
#define Hn 768
#define FFn 3072
#define Ln 6
#define BSn (Bn * Sn)       // 16384 tokens
#define CQ 512              // query chunk for attention scores buffer
#define LN_EPS 1e-5f

typedef __hip_bfloat16 bf16;
typedef __bf16 bf16x8 __attribute__((ext_vector_type(8)));
typedef float f32x4 __attribute__((ext_vector_type(4)));

__device__ __forceinline__ float b2f(bf16 v) { return __bfloat162float(v); }
__device__ __forceinline__ void stc(float* p, float v) { *p = v; }
__device__ __forceinline__ void stc(bf16* p, float v) { *p = __float2bfloat16(v); }

union Pk8 { float4 v; bf16 h[8]; };   // 8 consecutive bf16 = one 16B load

// async global->LDS, 16B per lane; LDS dest = wave-uniform base + lane*16
__device__ __forceinline__ void gld16(const bf16* g, short* l) {
  __builtin_amdgcn_global_load_lds(
      (const __attribute__((address_space(1))) unsigned int*)g,
      (__attribute__((address_space(3))) unsigned int*)l, 16, 0, 0);
}

// ---------------------------------------------------------------------------
// Embedding: x[b,s,:] = tok_emb[ids[b,s],:] + pos_emb[s,:]   (f32 in, f32 out)
// ---------------------------------------------------------------------------
__global__ void __launch_bounds__(256) embed_kernel(
    const int* __restrict__ ids, const float* __restrict__ tok,
    const float* __restrict__ pos, float* __restrict__ x) {
  long t = blockIdx.x;
  int s = (int)(t & (Sn - 1));
  long id = ids[t];
  const float* tr = tok + id * Hn;
  const float* pr = pos + (long)s * Hn;
  float* xr = x + t * Hn;
  for (int d = threadIdx.x; d < Hn; d += 256)
    xr[d] = tr[d] + pr[d];
}

// ---------------------------------------------------------------------------
// All-weights transpose + cast for one layer, single launch.
// Flat tile id -> {weight, tile}.  Tiles: Wq/Wk/Wv/Wo 576 each, W1 2304,
// W2 2304 => 6912 blocks total.
// Wt[n][k] = (bf16)W[k][n]; 32x32 tile, 256 threads (32x8), both coalesced.
// ---------------------------------------------------------------------------
__global__ void __launch_bounds__(256) transpose_all_kernel(
    const float* __restrict__ Wq_l, const float* __restrict__ Wk_l,
    const float* __restrict__ Wv_l, const float* __restrict__ Wo_l,
    const float* __restrict__ W1_l, const float* __restrict__ W2_l,
    bf16* __restrict__ wt) {
  int id = blockIdx.x;
  const float* W;
  bf16* Wt;
  int K, N, tile, tilesX;
  if (id < 2304) {                       // one of the 4 HxH weights
    int w = id / 576;
    tile = id - w * 576;
    W = (w == 0) ? Wq_l : (w == 1) ? Wk_l : (w == 2) ? Wv_l : Wo_l;
    Wt = wt + (size_t)w * Hn * Hn;
    K = Hn; N = Hn; tilesX = Hn / 32;
  } else if (id < 4608) {                // W1: [H][FF]
    tile = id - 2304;
    W = W1_l;
    Wt = wt + 4 * (size_t)Hn * Hn;
    K = Hn; N = FFn; tilesX = FFn / 32;
  } else {                               // W2: [FF][H]
    tile = id - 4608;
    W = W2_l;
    Wt = wt + 4 * (size_t)Hn * Hn + (size_t)Hn * FFn;
    K = FFn; N = Hn; tilesX = Hn / 32;
  }
  int n0 = (tile % tilesX) * 32, k0 = (tile / tilesX) * 32;

  __shared__ float t[32][33];
  int tx = threadIdx.x & 31, ty = threadIdx.x >> 5;  // ty 0..7
#pragma unroll
  for (int i = 0; i < 32; i += 8)
    t[ty + i][tx] = W[(long)(k0 + ty + i) * N + n0 + tx];
  __syncthreads();
#pragma unroll
  for (int i = 0; i < 32; i += 8)
    stc(Wt + (long)(n0 + ty + i) * K + k0 + tx, t[tx][ty + i]);
}

// ---------------------------------------------------------------------------
// LayerNorm: one 256-thread block per token. x: f32 in, out: bf16
// ---------------------------------------------------------------------------
__global__ void __launch_bounds__(256) ln_kernel(
    const float* __restrict__ x, const float* __restrict__ g,
    const float* __restrict__ b, bf16* __restrict__ out) {
  long token = blockIdx.x;
  const float* xr = x + token * Hn;
  bf16* orow = out + token * Hn;
  int tid = threadIdx.x;

  float vals[3];
  float s1 = 0.f;
#pragma unroll
  for (int i = 0; i < 3; i++) {
    vals[i] = xr[tid + 256 * i];
    s1 += vals[i];
  }
  __shared__ float sb[4];
  __shared__ float stat[2];
#pragma unroll
  for (int off = 32; off > 0; off >>= 1) s1 += __shfl_down(s1, off, 64);
  if ((tid & 63) == 0) sb[tid >> 6] = s1;
  __syncthreads();
  if (tid == 0) stat[0] = (sb[0] + sb[1] + sb[2] + sb[3]) * (1.0f / Hn);
  __syncthreads();
  float mean = stat[0];

  float s2 = 0.f;
#pragma unroll
  for (int i = 0; i < 3; i++) {
    float d = vals[i] - mean;
    s2 += d * d;
  }
#pragma unroll
  for (int off = 32; off > 0; off >>= 1) s2 += __shfl_down(s2, off, 64);
  if ((tid & 63) == 0) sb[tid >> 6] = s2;
  __syncthreads();
  if (tid == 0)
    stat[1] = rsqrtf((sb[0] + sb[1] + sb[2] + sb[3]) * (1.0f / Hn) + LN_EPS);
  __syncthreads();
  float inv = stat[1];

#pragma unroll
  for (int i = 0; i < 3; i++) {
    int d = tid + 256 * i;
    stc(orow + d, (vals[i] - mean) * inv * g[d] + b[d]);
  }
}

// ---------------------------------------------------------------------------
// MFMA GEMM: C[M,N] = epilogue(A[M,K] @ Bt[N,K]^T + bias[N] (+ res[M,N]))
//   A: bf16 row-major [M][K];  Bt: bf16 row-major [N][K] (= B^T);
//   bias: f32; res: f32; C: bf16 or f32.
//   EPI: 1 = bias + residual (f32 out), 2 = gelu(bias),
//        4 = fused QKV: N=2304; col<768 -> Q, <1536 -> K, else V^T store.
//            C = qb base; kb = C + BSn*Hn; vT = C + 2*BSn*Hn (bf16, [B][H][S])
//   1D grid with bijective XCD-chunked swizzle (8 XCDs) so blocks sharing an
//   A row-panel land on the same XCD's L2.
//   128x128 tile, BK=32, 4 waves (each 64x64 = 4x4 mfma_16x16x32 tiles).
//   Staging: global_load_lds 16B/lane; frags: ds_read_b128.
//   M%128==0, N%128==0, K%32==0, grid%8==0 assumed.
// ---------------------------------------------------------------------------
template <int EPI, typename CT>
__global__ void __launch_bounds__(256) mfma_gemm_kernel(
    const bf16* __restrict__ A, const bf16* __restrict__ Bt,
    const float* __restrict__ bias, const float* __restrict__ res,
    CT* __restrict__ C, int M, int N, int K,
    const float* __restrict__ bias2, const float* __restrict__ bias3) {
  __shared__ short As[128 * 32];   // [row][k] rows of 64B
  __shared__ short Bs[128 * 32];   // [col][k]
  int tid = threadIdx.x;
  int wave = tid >> 6, lane = tid & 63;
  int waveM = wave >> 1, waveN = wave & 1;
  int quad = lane >> 4, l16 = lane & 15;

  // bijective XCD-chunked swizzle (nwg % 8 == 0 for all our grids)
  int nwg = gridDim.x;
  int orig = blockIdx.x;
  int q8 = nwg >> 3, r8 = nwg & 7;
  int xcd = orig & 7, loc = orig >> 3;
  int wg = (xcd < r8 ? xcd * (q8 + 1) : r8 * (q8 + 1) + (xcd - r8) * q8) + loc;
  int gx = N >> 7;
  long colBase = (long)(wg % gx) * 128;
  long rowBase = (long)(wg / gx) * 128;

  const bf16* Ag = A + rowBase * K;
  const bf16* Bg = Bt + colBase * K;

  int srow = lane >> 2;           // 0..15 staging row within 16-row chunk
  int schunk = (lane & 3) * 8;    // 0,8,16,24 (k elements)

  f32x4 acc[4][4] = {};

  for (int kt = 0; kt < K; kt += 32) {
    // each wave stages 32 rows of A and 32 rows of B (2 x 16-row chunks)
#pragma unroll
    for (int c = 0; c < 2; c++) {
      int r0 = wave * 32 + c * 16;
      gld16(Ag + (long)(r0 + srow) * K + kt + schunk, &As[r0 * 32]);
      gld16(Bg + (long)(r0 + srow) * K + kt + schunk, &Bs[r0 * 32]);
    }
    __syncthreads();

    bf16x8 af[4], bfr[4];
#pragma unroll
    for (int t = 0; t < 4; t++)
      af[t] = *(const bf16x8*)&As[(waveM * 64 + t * 16 + l16) * 32 + quad * 8];
#pragma unroll
    for (int u = 0; u < 4; u++)
      bfr[u] = *(const bf16x8*)&Bs[(waveN * 64 + u * 16 + l16) * 32 + quad * 8];
#pragma unroll
    for (int t = 0; t < 4; t++)
#pragma unroll
      for (int u = 0; u < 4; u++)
        acc[t][u] = __builtin_amdgcn_mfma_f32_16x16x32_bf16(af[t], bfr[u],
                                                            acc[t][u], 0, 0, 0);
    __syncthreads();
  }

  // epilogue: D col=lane&15, row=quad*4+reg  [verified mapping]
#pragma unroll
  for (int t = 0; t < 4; t++) {
#pragma unroll
    for (int u = 0; u < 4; u++) {
      int col = (int)colBase + waveN * 64 + u * 16 + l16;
      if (EPI == 4) {
        long row0 = rowBase + waveM * 64 + t * 16 + quad * 4;
        if (col < 1536) {
          // Q or K: row-major [BSn][Hn] stores
          float bv = col < 768 ? bias[col] : bias2[col - 768];
          bf16* dst = (bf16*)C + (col < 768 ? 0 : (size_t)BSn * Hn - Hn);
#pragma unroll
          for (int r = 0; r < 4; r++)
            stc(dst + (row0 + r) * Hn + col, acc[t][u][r] + bv);
        } else {
          // V: transposed store into vT[B][Hn][Sn]
          int vcol = col - 1536;
          float bv = bias3[vcol];
          union { uint2 w; bf16 h[4]; } pk;
          long bb = row0 >> 11;          // token / Sn
          long s = row0 & (Sn - 1);      // token % Sn
#pragma unroll
          for (int r = 0; r < 4; r++)
            pk.h[r] = __float2bfloat16(acc[t][u][r] + bv);
          bf16* vT = (bf16*)C + 2 * (size_t)BSn * Hn;
          *reinterpret_cast<uint2*>(vT + (bb * Hn + vcol) * Sn + s) = pk.w;
        }
      } else {
        float bv = bias[col];
#pragma unroll
        for (int r = 0; r < 4; r++) {
          long row = rowBase + waveM * 64 + t * 16 + quad * 4 + r;
          float v = acc[t][u][r] + bv;
          if (EPI == 1) v += res[row * N + col];
          if (EPI == 2) v = 0.5f * v * (1.0f + erff(v * 0.70710678118654752f));
          stc(C + row * N + col, v);
        }
      }
    }
  }
}

// ---------------------------------------------------------------------------
// QK^T via MFMA: sc[b, qRel, k] = scale * dot(Q[b,q,:], K[b,k,:])
//   Q,K: [B][S][H] bf16 row-major; K rows are the natural Bt operand.
//   128x128 tile; causal early-out for fully masked tiles.
// ---------------------------------------------------------------------------
__global__ void __launch_bounds__(256) qk_mfma_kernel(
    const bf16* __restrict__ q, const bf16* __restrict__ k,
    bf16* __restrict__ sc, int q0) {
  int kBase = blockIdx.x * 128;
  int qBase = q0 + blockIdx.y * 128;   // absolute q
  if (kBase > qBase + 127) return;     // fully masked tile
  int b = blockIdx.z;
  const bf16* Ag = q + ((long)b * Sn + qBase) * Hn;
  const bf16* Bg = k + ((long)b * Sn + kBase) * Hn;

  __shared__ short As[128 * 32];
  __shared__ short Bs[128 * 32];
  int tid = threadIdx.x;
  int wave = tid >> 6, lane = tid & 63;
  int waveM = wave >> 1, waveN = wave & 1;
  int quad = lane >> 4, l16 = lane & 15;
  int srow = lane >> 2;
  int schunk = (lane & 3) * 8;

  f32x4 acc[4][4] = {};

  for (int kt = 0; kt < Hn; kt += 32) {
#pragma unroll
    for (int c = 0; c < 2; c++) {
      int r0 = wave * 32 + c * 16;
      gld16(Ag + (long)(r0 + srow) * Hn + kt + schunk, &As[r0 * 32]);
      gld16(Bg + (long)(r0 + srow) * Hn + kt + schunk, &Bs[r0 * 32]);
    }
    __syncthreads();

    bf16x8 af[4], bfr[4];
#pragma unroll
    for (int t = 0; t < 4; t++)
      af[t] = *(const bf16x8*)&As[(waveM * 64 + t * 16 + l16) * 32 + quad * 8];
#pragma unroll
    for (int u = 0; u < 4; u++)
      bfr[u] = *(const bf16x8*)&Bs[(waveN * 64 + u * 16 + l16) * 32 + quad * 8];
#pragma unroll
    for (int t = 0; t < 4; t++)
#pragma unroll
      for (int u = 0; u < 4; u++)
        acc[t][u] = __builtin_amdgcn_mfma_f32_16x16x32_bf16(af[t], bfr[u],
                                                            acc[t][u], 0, 0, 0);
    __syncthreads();
  }

  const float scale = 0.03608439182435161f;  // 1/sqrt(768)
#pragma unroll
  for (int t = 0; t < 4; t++)
#pragma unroll
    for (int u = 0; u < 4; u++) {
      int col = kBase + waveN * 64 + u * 16 + l16;
#pragma unroll
      for (int r = 0; r < 4; r++) {
        long qRel = (long)(qBase - q0) + waveM * 64 + t * 16 + quad * 4 + r;
        stc(sc + ((long)b * CQ + qRel) * Sn + col, acc[t][u][r] * scale);
      }
    }
}

// ---------------------------------------------------------------------------
// P @ V via MFMA: o[b,q,:] = P[b,qRel,:klimit] @ V[b,:klimit,:]
//   P: [B][CQ][Sn] bf16 (probs, zero-filled to 128-aligned limit);
//   vT: [B][Hn][Sn] bf16 (= V^T, written by fused QKV GEMM).
//   Causal: K-loop only to klimit = qBase+128.
// ---------------------------------------------------------------------------
__global__ void __launch_bounds__(256) pv_mfma_kernel(
    const bf16* __restrict__ p, const bf16* __restrict__ vT,
    bf16* __restrict__ o, int q0) {
  int colBase = blockIdx.x * 128;      // over Hn
  int qBase = q0 + blockIdx.y * 128;   // absolute q
  int b = blockIdx.z;
  int klimit = qBase + 128;            // multiple of 128
  const bf16* Ag = p + ((long)b * CQ + (qBase - q0)) * Sn;
  const bf16* Bg = vT + ((long)b * Hn + colBase) * Sn;

  __shared__ short As[128 * 32];
  __shared__ short Bs[128 * 32];
  int tid = threadIdx.x;
  int wave = tid >> 6, lane = tid & 63;
  int waveM = wave >> 1, waveN = wave & 1;
  int quad = lane >> 4, l16 = lane & 15;
  int srow = lane >> 2;
  int schunk = (lane & 3) * 8;

  f32x4 acc[4][4] = {};

  for (int kt = 0; kt < klimit; kt += 32) {
#pragma unroll
    for (int c = 0; c < 2; c++) {
      int r0 = wave * 32 + c * 16;
      gld16(Ag + (long)(r0 + srow) * Sn + kt + schunk, &As[r0 * 32]);
      gld16(Bg + (long)(r0 + srow) * Sn + kt + schunk, &Bs[r0 * 32]);
    }
    __syncthreads();

    bf16x8 af[4], bfr[4];
#pragma unroll
    for (int t = 0; t < 4; t++)
      af[t] = *(const bf16x8*)&As[(waveM * 64 + t * 16 + l16) * 32 + quad * 8];
#pragma unroll
    for (int u = 0; u < 4; u++)
      bfr[u] = *(const bf16x8*)&Bs[(waveN * 64 + u * 16 + l16) * 32 + quad * 8];
#pragma unroll
    for (int t = 0; t < 4; t++)
#pragma unroll
      for (int u = 0; u < 4; u++)
        acc[t][u] = __builtin_amdgcn_mfma_f32_16x16x32_bf16(af[t], bfr[u],
                                                            acc[t][u], 0, 0, 0);
    __syncthreads();
  }

#pragma unroll
  for (int t = 0; t < 4; t++)
#pragma unroll
    for (int u = 0; u < 4; u++) {
      int col = colBase + waveN * 64 + u * 16 + l16;
#pragma unroll
      for (int r = 0; r < 4; r++) {
        long qAbs = (long)qBase + waveM * 64 + t * 16 + quad * 4 + r;
        stc(o + ((long)b * Sn + qAbs) * Hn + col, acc[t][u][r]);
      }
    }
}

// ---------------------------------------------------------------------------
// Softmax over one score row (block per (qRel, b)) — vectorized bf16x8.
// Zero-fills [n, limit) with limit 128-aligned so PV's 128-wide K tiles
// never read stale garbage.
// ---------------------------------------------------------------------------
__global__ void __launch_bounds__(256) softmax_kernel(
    bf16* __restrict__ sc, const int* __restrict__ mask, int q0) {
  int qRel = blockIdx.x;
  int b = blockIdx.y;
  int qg = q0 + qRel;
  bf16* row = sc + ((long)b * CQ + qRel) * Sn;
  const int* mrow = mask + b * Sn;
  int tid = threadIdx.x;
  int n = qg + 1;
  int limit = (qg & ~127) + 128;   // 128-aligned zero-fill bound
  int k0 = tid * 8;

  Pk8 pk;
  pk.v = *reinterpret_cast<const float4*>(row + k0);
  int4 m0 = *reinterpret_cast<const int4*>(mrow + k0);
  int4 m1 = *reinterpret_cast<const int4*>(mrow + k0 + 4);
  int mm[8] = {m0.x, m0.y, m0.z, m0.w, m1.x, m1.y, m1.z, m1.w};

  float sv[8];
  float lmax = -1e30f;
#pragma unroll
  for (int j = 0; j < 8; j++) {
    int kk = k0 + j;
    float s = (kk < n && mm[j] != 0) ? b2f(pk.h[j]) : -1e30f;
    sv[j] = s;
    lmax = fmaxf(lmax, s);
  }
  __shared__ float sb[4];
  __shared__ float stat;
#pragma unroll
  for (int off = 32; off > 0; off >>= 1)
    lmax = fmaxf(lmax, __shfl_down(lmax, off, 64));
  if ((tid & 63) == 0) sb[tid >> 6] = lmax;
  __syncthreads();
  if (tid == 0) stat = fmaxf(fmaxf(sb[0], sb[1]), fmaxf(sb[2], sb[3]));
  __syncthreads();
  float gmax = stat;

  float ev[8];
  float lsum = 0.f;
#pragma unroll
  for (int j = 0; j < 8; j++) {
    float e = (sv[j] > -1e29f) ? __expf(sv[j] - gmax) : 0.f;
    ev[j] = e;
    lsum += e;
  }
#pragma unroll
  for (int off = 32; off > 0; off >>= 1) lsum += __shfl_down(lsum, off, 64);
  if ((tid & 63) == 0) sb[tid >> 6] = lsum;
  __syncthreads();
  if (tid == 0) stat = sb[0] + sb[1] + sb[2] + sb[3];
  __syncthreads();
  float inv = 1.0f / stat;

  if (k0 < limit) {   // group fully < limit (both multiples of 8)
    Pk8 o;
#pragma unroll
    for (int j = 0; j < 8; j++)
      o.h[j] = __float2bfloat16((k0 + j < n) ? ev[j] * inv : 0.f);
    *reinterpret_cast<float4*>(row + k0) = o.v;
  }
}

// ---------------------------------------------------------------------------
// Classifier head
// ---------------------------------------------------------------------------
__global__ void __launch_bounds__(256) cls_kernel(
    const bf16* __restrict__ h, const int* __restrict__ mask,
    const float* __restrict__ clsW, const float* __restrict__ clsb,
    float* __restrict__ out) {
  int b = blockIdx.x;
  int tid = threadIdx.x;
  __shared__ float sb[4];
  __shared__ int ib[4];
  __shared__ int lastsh;

  int ls = 0;
  for (int s = tid; s < Sn; s += 256) ls += mask[b * Sn + s];
#pragma unroll
  for (int off = 32; off > 0; off >>= 1) ls += __shfl_down(ls, off, 64);
  if ((tid & 63) == 0) ib[tid >> 6] = ls;
  __syncthreads();
  if (tid == 0) lastsh = ib[0] + ib[1] + ib[2] + ib[3] - 1;
  __syncthreads();
  int last = lastsh;

  const bf16* row = h + ((long)b * Sn + last) * Hn;
  float acc = 0.f;
  for (int d = tid; d < Hn; d += 256) acc += b2f(row[d]) * clsW[d];
#pragma unroll
  for (int off = 32; off > 0; off >>= 1) acc += __shfl_down(acc, off, 64);
  if ((tid & 63) == 0) sb[tid >> 6] = acc;
  __syncthreads();
  if (tid == 0) out[b] = sb[0] + sb[1] + sb[2] + sb[3] + clsb[0];
}

// ---------------------------------------------------------------------------
// Orchestration
// ---------------------------------------------------------------------------
extern "C" void kernel_launch(void* const* d_in, const int* in_sizes, int n_in,
                              void* d_out, int out_size, void* d_ws,
                              size_t ws_size, hipStream_t stream) {
  const int* ids     = (const int*)d_in[0];
  const int* mask    = (const int*)d_in[1];
  const float* tok   = (const float*)d_in[2];
  const float* pos   = (const float*)d_in[3];
  const float* Wq    = (const float*)d_in[4];
  const float* bq    = (const float*)d_in[5];
  const float* Wk    = (const float*)d_in[6];
  const float* bk    = (const float*)d_in[7];
  const float* Wv    = (const float*)d_in[8];
  const float* bv    = (const float*)d_in[9];
  const float* Wo    = (const float*)d_in[10];
  const float* bo    = (const float*)d_in[11];
  const float* ln1g  = (const float*)d_in[12];
  const float* ln1b  = (const float*)d_in[13];
  const float* ln2g  = (const float*)d_in[14];
  const float* ln2b  = (const float*)d_in[15];
  const float* W1    = (const float*)d_in[16];
  const float* b1    = (const float*)d_in[17];
  const float* W2    = (const float*)d_in[18];
  const float* b2    = (const float*)d_in[19];
  const float* flng  = (const float*)d_in[20];
  const float* flnb  = (const float*)d_in[21];
  const float* clsW  = (const float*)d_in[22];
  const float* clsb  = (const float*)d_in[23];

  // Workspace layout (~190 MB):
  //   x  : BS*H f32   (persistent hidden state)         50.3 MB
  //   h  : BS*H bf16  (LN output / attention output)    25.2 MB
  //   cb : BS*FF bf16 (q,k,vT + scores chunk; FFN mid) 100.7 MB
  //   wt : per-layer transposed bf16 weights            14.2 MB
  float* x = (float*)d_ws;
  bf16* h  = (bf16*)(x + (size_t)BSn * Hn);
  bf16* cb = h + (size_t)BSn * Hn;
  bf16* qb = cb;                          // [BSn][Hn]
  bf16* kb = cb + (size_t)BSn * Hn;       // [BSn][Hn]
  bf16* vtb = cb + 2 * (size_t)BSn * Hn;  // V^T [Bn][Hn][Sn]
  bf16* scb = cb + 3 * (size_t)BSn * Hn;  // [Bn, CQ, Sn] bf16 = 16.8 MB
  bf16* wt = cb + (size_t)BSn * FFn;
  bf16* wqT = wt;                                   // [H][H] (wq,wk,wv contiguous)
  bf16* woT = wqT + 3 * (size_t)Hn * Hn;
  bf16* w1T = woT + (size_t)Hn * Hn;                // [FF][H]
  bf16* w2T = w1T + (size_t)Hn * FFn;               // [H][FF]

  const int M = BSn;
  dim3 blk(256);
  dim3 gridQKV(3 * 2304 / 3);                   // 2304 blocks (N=2304, 1D)
  dim3 gridH1((Hn / 128) * (M / 128));          // 768 blocks
  dim3 gridF1((FFn / 128) * (M / 128));         // 3072 blocks
  dim3 gridQK(Sn / 128, CQ / 128, Bn);
  dim3 gridSM(CQ, Bn);
  dim3 gridPV(Hn / 128, CQ / 128, Bn);

  embed_kernel<<<BSn, blk, 0, stream>>>(ids, tok, pos, x);

  for (int l = 0; l < Ln; l++) {
    const float* Wq_l = Wq + (size_t)l * Hn * Hn;
    const float* Wk_l = Wk + (size_t)l * Hn * Hn;
    const float* Wv_l = Wv + (size_t)l * Hn * Hn;
    const float* Wo_l = Wo + (size_t)l * Hn * Hn;
    const float* W1_l = W1 + (size_t)l * Hn * FFn;
    const float* W2_l = W2 + (size_t)l * FFn * Hn;

    // all 6 weight transposes in one launch
    transpose_all_kernel<<<6912, blk, 0, stream>>>(Wq_l, Wk_l, Wv_l, Wo_l,
                                                   W1_l, W2_l, wt);

    // --- attention block ---
    ln_kernel<<<BSn, blk, 0, stream>>>(x, ln1g + l * Hn, ln1b + l * Hn, h);
    // fused QKV projection (N=2304); V stored transposed
    mfma_gemm_kernel<4, bf16><<<dim3(18 * (M / 128)), blk, 0, stream>>>(
        h, wqT, bq + l * Hn, nullptr, qb, M, 3 * Hn, Hn,
        bk + l * Hn, bv + l * Hn);
    for (int c = 0; c < Sn / CQ; c++) {
      int q0 = c * CQ;
      qk_mfma_kernel<<<gridQK, blk, 0, stream>>>(qb, kb, scb, q0);
      softmax_kernel<<<gridSM, blk, 0, stream>>>(scb, mask, q0);
      pv_mfma_kernel<<<gridPV, blk, 0, stream>>>(scb, vtb, h, q0);
    }
    mfma_gemm_kernel<1, float><<<gridH1, blk, 0, stream>>>(
        h, woT, bo + l * Hn, x, x, M, Hn, Hn, nullptr, nullptr);

    // --- FFN block ---
    ln_kernel<<<BSn, blk, 0, stream>>>(x, ln2g + l * Hn, ln2b + l * Hn, h);
    mfma_gemm_kernel<2, bf16><<<gridF1, blk, 0, stream>>>(
        h, w1T, b1 + l * FFn, nullptr, cb, M, FFn, Hn, nullptr, nullptr);
    mfma_gemm_kernel<1, float><<<gridH1, blk, 0, stream>>>(
        cb, w2T, b2 + l * Hn, x, x, M, Hn, FFn, nullptr, nullptr);
  }

  ln_kernel<<<BSn, blk, 0, stream>>>(x, flng, flnb, h);
  cls_kernel<<<Bn, blk, 0, stream>>>(h, mask, clsW, clsb, (float*)d_out);
}

// Round 3
// 4000.542 us; speedup vs baseline: 3.0643x; 1.1096x over previous
//
#include <hip/hip_runtime.h>
#include <hip/hip_bf16.h>

// Problem constants (BinaryClassifyModel: L=6, B=8, S=2048, H=768, V=32000)
#define Bn 8
#define Sn 2048
#define Hn 768
#define FFn 3072
#define Ln 6
#define BSn (Bn * Sn)       // 16384 tokens
#define CQ 512              // query chunk for attention scores buffer
#define LN_EPS 1e-5f

typedef __hip_bfloat16 bf16;
typedef __bf16 bf16x8 __attribute__((ext_vector_type(8)));
typedef float f32x4 __attribute__((ext_vector_type(4)));

__device__ __forceinline__ float b2f(bf16 v) { return __bfloat162float(v); }
__device__ __forceinline__ void stc(float* p, float v) { *p = v; }
__device__ __forceinline__ void stc(bf16* p, float v) { *p = __float2bfloat16(v); }

union Pk8 { float4 v; bf16 h[8]; };   // 8 consecutive bf16 = one 16B load

// async global->LDS, 16B per lane; LDS dest = wave-uniform base + lane*16
__device__ __forceinline__ void gld16(const bf16* g, short* l) {
  __builtin_amdgcn_global_load_lds(
      (const __attribute__((address_space(1))) unsigned int*)g,
      (__attribute__((address_space(3))) unsigned int*)l, 16, 0, 0);
}

#define BAR() __builtin_amdgcn_s_barrier()
#define LGKM0()                                            \
  {                                                        \
    asm volatile("s_waitcnt lgkmcnt(0)" ::: "memory");     \
    __builtin_amdgcn_sched_barrier(0);                     \
  }
#define VMC(n) asm volatile("s_waitcnt vmcnt(" #n ")" ::: "memory")

// ---------------------------------------------------------------------------
// Embedding
// ---------------------------------------------------------------------------
__global__ void __launch_bounds__(256) embed_kernel(
    const int* __restrict__ ids, const float* __restrict__ tok,
    const float* __restrict__ pos, float* __restrict__ x) {
  long t = blockIdx.x;
  int s = (int)(t & (Sn - 1));
  long id = ids[t];
  const float* tr = tok + id * Hn;
  const float* pr = pos + (long)s * Hn;
  float* xr = x + t * Hn;
  for (int d = threadIdx.x; d < Hn; d += 256)
    xr[d] = tr[d] + pr[d];
}

// ---------------------------------------------------------------------------
// All-weights transpose + cast for one layer, single launch (6912 blocks).
// ---------------------------------------------------------------------------
__global__ void __launch_bounds__(256) transpose_all_kernel(
    const float* __restrict__ Wq_l, const float* __restrict__ Wk_l,
    const float* __restrict__ Wv_l, const float* __restrict__ Wo_l,
    const float* __restrict__ W1_l, const float* __restrict__ W2_l,
    bf16* __restrict__ wt) {
  int id = blockIdx.x;
  const float* W;
  bf16* Wt;
  int K, N, tile, tilesX;
  if (id < 2304) {
    int w = id / 576;
    tile = id - w * 576;
    W = (w == 0) ? Wq_l : (w == 1) ? Wk_l : (w == 2) ? Wv_l : Wo_l;
    Wt = wt + (size_t)w * Hn * Hn;
    K = Hn; N = Hn; tilesX = Hn / 32;
  } else if (id < 4608) {
    tile = id - 2304;
    W = W1_l;
    Wt = wt + 4 * (size_t)Hn * Hn;
    K = Hn; N = FFn; tilesX = FFn / 32;
  } else {
    tile = id - 4608;
    W = W2_l;
    Wt = wt + 4 * (size_t)Hn * Hn + (size_t)Hn * FFn;
    K = FFn; N = Hn; tilesX = Hn / 32;
  }
  int n0 = (tile % tilesX) * 32, k0 = (tile / tilesX) * 32;

  __shared__ float t[32][33];
  int tx = threadIdx.x & 31, ty = threadIdx.x >> 5;
#pragma unroll
  for (int i = 0; i < 32; i += 8)
    t[ty + i][tx] = W[(long)(k0 + ty + i) * N + n0 + tx];
  __syncthreads();
#pragma unroll
  for (int i = 0; i < 32; i += 8)
    stc(Wt + (long)(n0 + ty + i) * K + k0 + tx, t[tx][ty + i]);
}

// ---------------------------------------------------------------------------
// LayerNorm
// ---------------------------------------------------------------------------
__global__ void __launch_bounds__(256) ln_kernel(
    const float* __restrict__ x, const float* __restrict__ g,
    const float* __restrict__ b, bf16* __restrict__ out) {
  long token = blockIdx.x;
  const float* xr = x + token * Hn;
  bf16* orow = out + token * Hn;
  int tid = threadIdx.x;

  float vals[3];
  float s1 = 0.f;
#pragma unroll
  for (int i = 0; i < 3; i++) {
    vals[i] = xr[tid + 256 * i];
    s1 += vals[i];
  }
  __shared__ float sb[4];
  __shared__ float stat[2];
#pragma unroll
  for (int off = 32; off > 0; off >>= 1) s1 += __shfl_down(s1, off, 64);
  if ((tid & 63) == 0) sb[tid >> 6] = s1;
  __syncthreads();
  if (tid == 0) stat[0] = (sb[0] + sb[1] + sb[2] + sb[3]) * (1.0f / Hn);
  __syncthreads();
  float mean = stat[0];

  float s2 = 0.f;
#pragma unroll
  for (int i = 0; i < 3; i++) {
    float d = vals[i] - mean;
    s2 += d * d;
  }
#pragma unroll
  for (int off = 32; off > 0; off >>= 1) s2 += __shfl_down(s2, off, 64);
  if ((tid & 63) == 0) sb[tid >> 6] = s2;
  __syncthreads();
  if (tid == 0)
    stat[1] = rsqrtf((sb[0] + sb[1] + sb[2] + sb[3]) * (1.0f / Hn) + LN_EPS);
  __syncthreads();
  float inv = stat[1];

#pragma unroll
  for (int i = 0; i < 3; i++) {
    int d = tid + 256 * i;
    stc(orow + d, (vals[i] - mean) * inv * g[d] + b[d]);
  }
}

// ---------------------------------------------------------------------------
// 256x256 8-phase MFMA GEMM (T2+T3+T4+T5).  C = epi(A @ Bt^T + bias [+res])
//   A: bf16 [M][K]; Bt: bf16 [N][K]; 512 threads = 8 waves (2M x 4N).
//   BK=64, double-buffered LDS (128 KiB), one half-tile (16 KB) staged per
//   phase via global_load_lds with inverse-swizzled source; reads use
//   byte ^= (row&7)<<4.  vmcnt(6) once per K-tile (counted, not drained).
//   EPI: 1 = bias+res (f32 out), 2 = gelu(bias) (bf16), 4 = fused QKV.
//   Assumes M%256==0, N%256==0, K%128==0, grid%8==0, K/64 >= 2.
// ---------------------------------------------------------------------------
template <int EPI, typename CT>
__global__ void __launch_bounds__(512) gemm256_kernel(
    const bf16* __restrict__ A, const bf16* __restrict__ Bt,
    const float* __restrict__ bias, const float* __restrict__ res,
    CT* __restrict__ C, int M, int N, int K,
    const float* __restrict__ bias2, const float* __restrict__ bias3) {
  __shared__ short lds[65536];  // buf b: A at b*32768, B at b*32768+16384
  int tid = threadIdx.x;
  int wave = tid >> 6, lane = tid & 63;
  int wm = wave >> 2, wn = wave & 3;   // 2 x 4 wave grid
  int quad = lane >> 4, l16 = lane & 15;
  int swz = (l16 & 7) << 4;            // read-side XOR (bytes)
  int g = lane >> 3;                   // staging: row within 8-row chunk
  int kswz = ((lane & 7) ^ g) * 8;     // staging: pre-swizzled k-offset (elems)

  // bijective XCD-chunked swizzle (grid%8==0 for all our launches)
  int nwg = gridDim.x, orig = blockIdx.x;
  int q8 = nwg >> 3, r8 = nwg & 7;
  int xcd = orig & 7, loc = orig >> 3;
  int wg = (xcd < r8 ? xcd * (q8 + 1) : r8 * (q8 + 1) + (xcd - r8) * q8) + loc;
  int gx = N >> 8;
  long colBase = (long)(wg % gx) * 256;
  long rowBase = (long)(wg / gx) * 256;

  const bf16* Ag = A + rowBase * K;
  const bf16* Bg = Bt + colBase * K;

  f32x4 acc[8][4] = {};
  bf16x8 af[4][2], bfr[2][2][2];

// stage one 16KB half-tile (2 x 1KB chunk per wave).
// A halves: odd=0 -> rows {0-63,128-191}; odd=1 -> {64-127,192-255}
// B halves: odd=0 -> rows {0-31,64-95,128-159,192-223}; odd=1 -> +32
#define STAGEA(T, odd)                                                     \
  {                                                                        \
    short* base_ = lds + ((T) & 1) * 32768;                                \
    long kt_ = (long)(T) * 64;                                             \
    _Pragma("unroll") for (int j_ = 0; j_ < 2; j_++) {                     \
      int c_ = wave * 2 + j_;                                              \
      int r0_ = (odd) * 64 + ((c_ >> 3) << 7) + ((c_ & 7) << 3);           \
      gld16(Ag + (long)(r0_ + g) * K + kt_ + kswz, base_ + r0_ * 64);      \
    }                                                                      \
  }
#define STAGEB(T, odd)                                                     \
  {                                                                        \
    short* base_ = lds + ((T) & 1) * 32768 + 16384;                        \
    long kt_ = (long)(T) * 64;                                             \
    _Pragma("unroll") for (int j_ = 0; j_ < 2; j_++) {                     \
      int c_ = wave * 2 + j_;                                              \
      int r0_ = (odd) * 32 + ((c_ >> 2) << 6) + ((c_ & 3) << 3);           \
      gld16(Bg + (long)(r0_ + g) * K + kt_ + kswz, base_ + r0_ * 64);      \
    }                                                                      \
  }
#define LOADA(T, h)                                                        \
  {                                                                        \
    const char* base_ = (const char*)(lds + ((T) & 1) * 32768);            \
    _Pragma("unroll") for (int i_ = 0; i_ < 4; i_++) {                     \
      const char* rp_ = base_ + (wm * 128 + (h) * 64 + i_ * 16 + l16) * 128; \
      _Pragma("unroll") for (int s_ = 0; s_ < 2; s_++)                     \
          af[i_][s_] = *(const bf16x8*)(rp_ + ((s_ * 64 + quad * 16) ^ swz)); \
    }                                                                      \
  }
#define LOADB(T, nh)                                                       \
  {                                                                        \
    const char* base_ = (const char*)(lds + ((T) & 1) * 32768 + 16384);    \
    _Pragma("unroll") for (int j_ = 0; j_ < 2; j_++) {                     \
      const char* rp_ = base_ + (wn * 64 + (nh) * 32 + j_ * 16 + l16) * 128; \
      _Pragma("unroll") for (int s_ = 0; s_ < 2; s_++)                     \
          bfr[nh][j_][s_] = *(const bf16x8*)(rp_ + ((s_ * 64 + quad * 16) ^ swz)); \
    }                                                                      \
  }
#define MFMA_PH(h, nh)                                                     \
  __builtin_amdgcn_s_setprio(1);                                           \
  _Pragma("unroll") for (int i_ = 0; i_ < 4; i_++)                         \
      _Pragma("unroll") for (int j_ = 0; j_ < 2; j_++)                     \
          _Pragma("unroll") for (int s_ = 0; s_ < 2; s_++)                 \
              acc[(h) * 4 + i_][(nh) * 2 + j_] =                           \
                  __builtin_amdgcn_mfma_f32_16x16x32_bf16(                 \
                      af[i_][s_], bfr[nh][j_][s_],                         \
                      acc[(h) * 4 + i_][(nh) * 2 + j_], 0, 0, 0);          \
  __builtin_amdgcn_s_setprio(0);

  int NT = K >> 6;
  // prologue: tile0 complete + H0,H1,H2 of tile1  (14 loads/wave)
  STAGEA(0, 0); STAGEB(0, 0); STAGEB(0, 1); STAGEA(0, 1);
  STAGEA(1, 0); STAGEB(1, 0); STAGEB(1, 1);
  VMC(6);   // newest 6 = tile1's 3 half-tiles -> tile0 fully landed
  BAR();

  for (int T = 0; T < NT; T++) {
    // q0: read A-even + B-even of T; stage H3(T+1) (A-odd, other buffer)
    LOADA(T, 0); LOADB(T, 0);
    if (T + 1 < NT) STAGEA(T + 1, 1);
    BAR(); LGKM0(); MFMA_PH(0, 0); BAR();
    // q1: read B-odd of T; stage H0(T+2) (A-even, this buffer, free after q0)
    LOADB(T, 1);
    if (T + 2 < NT) STAGEA(T + 2, 0);
    BAR(); LGKM0(); MFMA_PH(0, 1); BAR();
    // q2: read A-odd of T; stage H1(T+2) (B-even, free after q0)
    LOADA(T, 1);
    if (T + 2 < NT) STAGEB(T + 2, 0);
    BAR(); LGKM0(); MFMA_PH(1, 1); BAR();
    // q3: no reads; stage H2(T+2) (B-odd, free after q1); counted vmcnt
    if (T + 2 < NT) { STAGEB(T + 2, 1); VMC(6); }
    else { VMC(0); }
    BAR(); MFMA_PH(1, 0); BAR();
  }

  // epilogue: D col=lane&15, row=quad*4+reg
#pragma unroll
  for (int mi = 0; mi < 8; mi++) {
#pragma unroll
    for (int nj = 0; nj < 4; nj++) {
      int col = (int)colBase + wn * 64 + nj * 16 + l16;
      long row0 = rowBase + wm * 128 + mi * 16 + quad * 4;
      if (EPI == 4) {
        if (col < 1536) {
          float bv = col < 768 ? bias[col] : bias2[col - 768];
          bf16* dst = (bf16*)C + (col < 768 ? 0 : (size_t)BSn * Hn - Hn);
#pragma unroll
          for (int r = 0; r < 4; r++)
            stc(dst + (row0 + r) * Hn + col, acc[mi][nj][r] + bv);
        } else {
          int vcol = col - 1536;
          float bv = bias3[vcol];
          union { uint2 w; bf16 h[4]; } pk;
          long bb = row0 >> 11;          // token / Sn
          long s = row0 & (Sn - 1);      // token % Sn
#pragma unroll
          for (int r = 0; r < 4; r++)
            pk.h[r] = __float2bfloat16(acc[mi][nj][r] + bv);
          bf16* vT = (bf16*)C + 2 * (size_t)BSn * Hn;
          *reinterpret_cast<uint2*>(vT + (bb * Hn + vcol) * Sn + s) = pk.w;
        }
      } else {
        float bv = bias[col];
#pragma unroll
        for (int r = 0; r < 4; r++) {
          long row = row0 + r;
          float v = acc[mi][nj][r] + bv;
          if (EPI == 1) v += res[row * N + col];
          if (EPI == 2) v = 0.5f * v * (1.0f + erff(v * 0.70710678118654752f));
          stc(C + row * N + col, v);
        }
      }
    }
  }
#undef STAGEA
#undef STAGEB
#undef LOADA
#undef LOADB
#undef MFMA_PH
}

// ---------------------------------------------------------------------------
// QK^T via MFMA (128x128, causal early-out)
// ---------------------------------------------------------------------------
__global__ void __launch_bounds__(256) qk_mfma_kernel(
    const bf16* __restrict__ q, const bf16* __restrict__ k,
    bf16* __restrict__ sc, int q0) {
  int kBase = blockIdx.x * 128;
  int qBase = q0 + blockIdx.y * 128;
  if (kBase > qBase + 127) return;
  int b = blockIdx.z;
  const bf16* Ag = q + ((long)b * Sn + qBase) * Hn;
  const bf16* Bg = k + ((long)b * Sn + kBase) * Hn;

  __shared__ short As[128 * 32];
  __shared__ short Bs[128 * 32];
  int tid = threadIdx.x;
  int wave = tid >> 6, lane = tid & 63;
  int waveM = wave >> 1, waveN = wave & 1;
  int quad = lane >> 4, l16 = lane & 15;
  int srow = lane >> 2;
  int schunk = (lane & 3) * 8;

  f32x4 acc[4][4] = {};

  for (int kt = 0; kt < Hn; kt += 32) {
#pragma unroll
    for (int c = 0; c < 2; c++) {
      int r0 = wave * 32 + c * 16;
      gld16(Ag + (long)(r0 + srow) * Hn + kt + schunk, &As[r0 * 32]);
      gld16(Bg + (long)(r0 + srow) * Hn + kt + schunk, &Bs[r0 * 32]);
    }
    __syncthreads();

    bf16x8 af[4], bfrg[4];
#pragma unroll
    for (int t = 0; t < 4; t++)
      af[t] = *(const bf16x8*)&As[(waveM * 64 + t * 16 + l16) * 32 + quad * 8];
#pragma unroll
    for (int u = 0; u < 4; u++)
      bfrg[u] = *(const bf16x8*)&Bs[(waveN * 64 + u * 16 + l16) * 32 + quad * 8];
#pragma unroll
    for (int t = 0; t < 4; t++)
#pragma unroll
      for (int u = 0; u < 4; u++)
        acc[t][u] = __builtin_amdgcn_mfma_f32_16x16x32_bf16(af[t], bfrg[u],
                                                            acc[t][u], 0, 0, 0);
    __syncthreads();
  }

  const float scale = 0.03608439182435161f;  // 1/sqrt(768)
#pragma unroll
  for (int t = 0; t < 4; t++)
#pragma unroll
    for (int u = 0; u < 4; u++) {
      int col = kBase + waveN * 64 + u * 16 + l16;
#pragma unroll
      for (int r = 0; r < 4; r++) {
        long qRel = (long)(qBase - q0) + waveM * 64 + t * 16 + quad * 4 + r;
        stc(sc + ((long)b * CQ + qRel) * Sn + col, acc[t][u][r] * scale);
      }
    }
}

// ---------------------------------------------------------------------------
// P @ V via MFMA (128x128; vT operand; causal K-limit)
// ---------------------------------------------------------------------------
__global__ void __launch_bounds__(256) pv_mfma_kernel(
    const bf16* __restrict__ p, const bf16* __restrict__ vT,
    bf16* __restrict__ o, int q0) {
  int colBase = blockIdx.x * 128;
  int qBase = q0 + blockIdx.y * 128;
  int b = blockIdx.z;
  int klimit = qBase + 128;
  const bf16* Ag = p + ((long)b * CQ + (qBase - q0)) * Sn;
  const bf16* Bg = vT + ((long)b * Hn + colBase) * Sn;

  __shared__ short As[128 * 32];
  __shared__ short Bs[128 * 32];
  int tid = threadIdx.x;
  int wave = tid >> 6, lane = tid & 63;
  int waveM = wave >> 1, waveN = wave & 1;
  int quad = lane >> 4, l16 = lane & 15;
  int srow = lane >> 2;
  int schunk = (lane & 3) * 8;

  f32x4 acc[4][4] = {};

  for (int kt = 0; kt < klimit; kt += 32) {
#pragma unroll
    for (int c = 0; c < 2; c++) {
      int r0 = wave * 32 + c * 16;
      gld16(Ag + (long)(r0 + srow) * Sn + kt + schunk, &As[r0 * 32]);
      gld16(Bg + (long)(r0 + srow) * Sn + kt + schunk, &Bs[r0 * 32]);
    }
    __syncthreads();

    bf16x8 af[4], bfrg[4];
#pragma unroll
    for (int t = 0; t < 4; t++)
      af[t] = *(const bf16x8*)&As[(waveM * 64 + t * 16 + l16) * 32 + quad * 8];
#pragma unroll
    for (int u = 0; u < 4; u++)
      bfrg[u] = *(const bf16x8*)&Bs[(waveN * 64 + u * 16 + l16) * 32 + quad * 8];
#pragma unroll
    for (int t = 0; t < 4; t++)
#pragma unroll
      for (int u = 0; u < 4; u++)
        acc[t][u] = __builtin_amdgcn_mfma_f32_16x16x32_bf16(af[t], bfrg[u],
                                                            acc[t][u], 0, 0, 0);
    __syncthreads();
  }

#pragma unroll
  for (int t = 0; t < 4; t++)
#pragma unroll
    for (int u = 0; u < 4; u++) {
      int col = colBase + waveN * 64 + u * 16 + l16;
#pragma unroll
      for (int r = 0; r < 4; r++) {
        long qAbs = (long)qBase + waveM * 64 + t * 16 + quad * 4 + r;
        stc(o + ((long)b * Sn + qAbs) * Hn + col, acc[t][u][r]);
      }
    }
}

// ---------------------------------------------------------------------------
// Softmax (vectorized bf16x8); zero-fills to 128-aligned limit for PV.
// ---------------------------------------------------------------------------
__global__ void __launch_bounds__(256) softmax_kernel(
    bf16* __restrict__ sc, const int* __restrict__ mask, int q0) {
  int qRel = blockIdx.x;
  int b = blockIdx.y;
  int qg = q0 + qRel;
  bf16* row = sc + ((long)b * CQ + qRel) * Sn;
  const int* mrow = mask + b * Sn;
  int tid = threadIdx.x;
  int n = qg + 1;
  int limit = (qg & ~127) + 128;
  int k0 = tid * 8;

  Pk8 pk;
  pk.v = *reinterpret_cast<const float4*>(row + k0);
  int4 m0 = *reinterpret_cast<const int4*>(mrow + k0);
  int4 m1 = *reinterpret_cast<const int4*>(mrow + k0 + 4);
  int mm[8] = {m0.x, m0.y, m0.z, m0.w, m1.x, m1.y, m1.z, m1.w};

  float sv[8];
  float lmax = -1e30f;
#pragma unroll
  for (int j = 0; j < 8; j++) {
    int kk = k0 + j;
    float s = (kk < n && mm[j] != 0) ? b2f(pk.h[j]) : -1e30f;
    sv[j] = s;
    lmax = fmaxf(lmax, s);
  }
  __shared__ float sb[4];
  __shared__ float stat;
#pragma unroll
  for (int off = 32; off > 0; off >>= 1)
    lmax = fmaxf(lmax, __shfl_down(lmax, off, 64));
  if ((tid & 63) == 0) sb[tid >> 6] = lmax;
  __syncthreads();
  if (tid == 0) stat = fmaxf(fmaxf(sb[0], sb[1]), fmaxf(sb[2], sb[3]));
  __syncthreads();
  float gmax = stat;

  float ev[8];
  float lsum = 0.f;
#pragma unroll
  for (int j = 0; j < 8; j++) {
    float e = (sv[j] > -1e29f) ? __expf(sv[j] - gmax) : 0.f;
    ev[j] = e;
    lsum += e;
  }
#pragma unroll
  for (int off = 32; off > 0; off >>= 1) lsum += __shfl_down(lsum, off, 64);
  if ((tid & 63) == 0) sb[tid >> 6] = lsum;
  __syncthreads();
  if (tid == 0) stat = sb[0] + sb[1] + sb[2] + sb[3];
  __syncthreads();
  float inv = 1.0f / stat;

  if (k0 < limit) {
    Pk8 o;
#pragma unroll
    for (int j = 0; j < 8; j++)
      o.h[j] = __float2bfloat16((k0 + j < n) ? ev[j] * inv : 0.f);
    *reinterpret_cast<float4*>(row + k0) = o.v;
  }
}

// ---------------------------------------------------------------------------
// Classifier head
// ---------------------------------------------------------------------------
__global__ void __launch_bounds__(256) cls_kernel(
    const bf16* __restrict__ h, const int* __restrict__ mask,
    const float* __restrict__ clsW, const float* __restrict__ clsb,
    float* __restrict__ out) {
  int b = blockIdx.x;
  int tid = threadIdx.x;
  __shared__ float sb[4];
  __shared__ int ib[4];
  __shared__ int lastsh;

  int ls = 0;
  for (int s = tid; s < Sn; s += 256) ls += mask[b * Sn + s];
#pragma unroll
  for (int off = 32; off > 0; off >>= 1) ls += __shfl_down(ls, off, 64);
  if ((tid & 63) == 0) ib[tid >> 6] = ls;
  __syncthreads();
  if (tid == 0) lastsh = ib[0] + ib[1] + ib[2] + ib[3] - 1;
  __syncthreads();
  int last = lastsh;

  const bf16* row = h + ((long)b * Sn + last) * Hn;
  float acc = 0.f;
  for (int d = tid; d < Hn; d += 256) acc += b2f(row[d]) * clsW[d];
#pragma unroll
  for (int off = 32; off > 0; off >>= 1) acc += __shfl_down(acc, off, 64);
  if ((tid & 63) == 0) sb[tid >> 6] = acc;
  __syncthreads();
  if (tid == 0) out[b] = sb[0] + sb[1] + sb[2] + sb[3] + clsb[0];
}

// ---------------------------------------------------------------------------
// Orchestration
// ---------------------------------------------------------------------------
extern "C" void kernel_launch(void* const* d_in, const int* in_sizes, int n_in,
                              void* d_out, int out_size, void* d_ws,
                              size_t ws_size, hipStream_t stream) {
  const int* ids     = (const int*)d_in[0];
  const int* mask    = (const int*)d_in[1];
  const float* tok   = (const float*)d_in[2];
  const float* pos   = (const float*)d_in[3];
  const float* Wq    = (const float*)d_in[4];
  const float* bq    = (const float*)d_in[5];
  const float* Wk    = (const float*)d_in[6];
  const float* bk    = (const float*)d_in[7];
  const float* Wv    = (const float*)d_in[8];
  const float* bv    = (const float*)d_in[9];
  const float* Wo    = (const float*)d_in[10];
  const float* bo    = (const float*)d_in[11];
  const float* ln1g  = (const float*)d_in[12];
  const float* ln1b  = (const float*)d_in[13];
  const float* ln2g  = (const float*)d_in[14];
  const float* ln2b  = (const float*)d_in[15];
  const float* W1    = (const float*)d_in[16];
  const float* b1    = (const float*)d_in[17];
  const float* W2    = (const float*)d_in[18];
  const float* b2    = (const float*)d_in[19];
  const float* flng  = (const float*)d_in[20];
  const float* flnb  = (const float*)d_in[21];
  const float* clsW  = (const float*)d_in[22];
  const float* clsb  = (const float*)d_in[23];

  float* x = (float*)d_ws;
  bf16* h  = (bf16*)(x + (size_t)BSn * Hn);
  bf16* cb = h + (size_t)BSn * Hn;
  bf16* qb = cb;                          // [BSn][Hn]
  bf16* kb = cb + (size_t)BSn * Hn;       // [BSn][Hn]
  bf16* vtb = cb + 2 * (size_t)BSn * Hn;  // V^T [Bn][Hn][Sn]
  bf16* scb = cb + 3 * (size_t)BSn * Hn;  // [Bn, CQ, Sn]
  bf16* wt = cb + (size_t)BSn * FFn;
  bf16* wqT = wt;                                   // wq,wk,wv contiguous
  bf16* woT = wqT + 3 * (size_t)Hn * Hn;
  bf16* w1T = woT + (size_t)Hn * Hn;                // [FF][H]
  bf16* w2T = w1T + (size_t)Hn * FFn;               // [H][FF]

  const int M = BSn;
  dim3 blk(256);
  dim3 blk512(512);
  dim3 gridQK(Sn / 128, CQ / 128, Bn);
  dim3 gridSM(CQ, Bn);
  dim3 gridPV(Hn / 128, CQ / 128, Bn);

  embed_kernel<<<BSn, blk, 0, stream>>>(ids, tok, pos, x);

  for (int l = 0; l < Ln; l++) {
    const float* Wq_l = Wq + (size_t)l * Hn * Hn;
    const float* Wk_l = Wk + (size_t)l * Hn * Hn;
    const float* Wv_l = Wv + (size_t)l * Hn * Hn;
    const float* Wo_l = Wo + (size_t)l * Hn * Hn;
    const float* W1_l = W1 + (size_t)l * Hn * FFn;
    const float* W2_l = W2 + (size_t)l * FFn * Hn;

    transpose_all_kernel<<<6912, blk, 0, stream>>>(Wq_l, Wk_l, Wv_l, Wo_l,
                                                   W1_l, W2_l, wt);

    // --- attention block ---
    ln_kernel<<<BSn, blk, 0, stream>>>(x, ln1g + l * Hn, ln1b + l * Hn, h);
    // fused QKV (M=16384, N=2304, K=768): 64*9 = 576 blocks
    gemm256_kernel<4, bf16><<<576, blk512, 0, stream>>>(
        h, wqT, bq + l * Hn, nullptr, qb, M, 3 * Hn, Hn,
        bk + l * Hn, bv + l * Hn);
    for (int c = 0; c < Sn / CQ; c++) {
      int q0 = c * CQ;
      qk_mfma_kernel<<<gridQK, blk, 0, stream>>>(qb, kb, scb, q0);
      softmax_kernel<<<gridSM, blk, 0, stream>>>(scb, mask, q0);
      pv_mfma_kernel<<<gridPV, blk, 0, stream>>>(scb, vtb, h, q0);
    }
    // Wo (N=768, K=768): 64*3 = 192 blocks
    gemm256_kernel<1, float><<<192, blk512, 0, stream>>>(
        h, woT, bo + l * Hn, x, x, M, Hn, Hn, nullptr, nullptr);

    // --- FFN block ---
    ln_kernel<<<BSn, blk, 0, stream>>>(x, ln2g + l * Hn, ln2b + l * Hn, h);
    // W1 (N=3072, K=768): 64*12 = 768 blocks
    gemm256_kernel<2, bf16><<<768, blk512, 0, stream>>>(
        h, w1T, b1 + l * FFn, nullptr, cb, M, FFn, Hn, nullptr, nullptr);
    // W2 (N=768, K=3072): 192 blocks
    gemm256_kernel<1, float><<<192, blk512, 0, stream>>>(
        cb, w2T, b2 + l * Hn, x, x, M, Hn, FFn, nullptr, nullptr);
  }

  ln_kernel<<<BSn, blk, 0, stream>>>(x, flng, flnb, h);
  cls_kernel<<<Bn, blk, 0, stream>>>(h, mask, clsW, clsb, (float*)d_out);
}

// Round 5
// 3925.429 us; speedup vs baseline: 3.1230x; 1.0191x over previous
//
#include <hip/hip_runtime.h>
#include <hip/hip_bf16.h>

// Problem constants (BinaryClassifyModel: L=6, B=8, S=2048, H=768, V=32000)
#define Bn 8
#define Sn 2048
#define Hn 768
#define FFn 3072
#define Ln 6
#define BSn (Bn * Sn)       // 16384 tokens
#define CQ 512              // query chunk for attention scores buffer
#define LN_EPS 1e-5f

typedef __hip_bfloat16 bf16;
typedef __bf16 bf16x8 __attribute__((ext_vector_type(8)));
typedef float f32x4 __attribute__((ext_vector_type(4)));

__device__ __forceinline__ float b2f(bf16 v) { return __bfloat162float(v); }
__device__ __forceinline__ void stc(float* p, float v) { *p = v; }
__device__ __forceinline__ void stc(bf16* p, float v) { *p = __float2bfloat16(v); }

union Pk8 { float4 v; bf16 h[8]; };   // 8 consecutive bf16 = one 16B load

// async global->LDS, 16B per lane; LDS dest = wave-uniform base + lane*16
__device__ __forceinline__ void gld16(const bf16* g, short* l) {
  __builtin_amdgcn_global_load_lds(
      (const __attribute__((address_space(1))) unsigned int*)g,
      (__attribute__((address_space(3))) unsigned int*)l, 16, 0, 0);
}

#define BAR() __builtin_amdgcn_s_barrier()
#define LGKM0()                                            \
  {                                                        \
    asm volatile("s_waitcnt lgkmcnt(0)" ::: "memory");     \
    __builtin_amdgcn_sched_barrier(0);                     \
  }
#define VMC(n) asm volatile("s_waitcnt vmcnt(" #n ")" ::: "memory")

// exact-GELU via A&S 7.1.26 erf polynomial on v/sqrt(2), |eps| <= 1.5e-7
__device__ __forceinline__ float gelu_exact(float v) {
  float a = fabsf(v) * 0.70710678118654752f;   // |v| / sqrt(2)
  float t = 1.0f / (1.0f + 0.3275911f * a);
  float poly = t * (0.254829592f +
               t * (-0.284496736f +
               t * (1.421413741f +
               t * (-1.453152027f + t * 1.061405429f))));
  float er = 1.0f - poly * __expf(-a * a);
  er = v < 0.f ? -er : er;
  return 0.5f * v * (1.0f + er);
}

// ---------------------------------------------------------------------------
// Embedding
// ---------------------------------------------------------------------------
__global__ void __launch_bounds__(256) embed_kernel(
    const int* __restrict__ ids, const float* __restrict__ tok,
    const float* __restrict__ pos, float* __restrict__ x) {
  long t = blockIdx.x;
  int s = (int)(t & (Sn - 1));
  long id = ids[t];
  const float* tr = tok + id * Hn;
  const float* pr = pos + (long)s * Hn;
  float* xr = x + t * Hn;
  for (int d = threadIdx.x; d < Hn; d += 256)
    xr[d] = tr[d] + pr[d];
}

// ---------------------------------------------------------------------------
// All-weights transpose + cast for one layer, single launch (6912 blocks).
// ---------------------------------------------------------------------------
__global__ void __launch_bounds__(256) transpose_all_kernel(
    const float* __restrict__ Wq_l, const float* __restrict__ Wk_l,
    const float* __restrict__ Wv_l, const float* __restrict__ Wo_l,
    const float* __restrict__ W1_l, const float* __restrict__ W2_l,
    bf16* __restrict__ wt) {
  int id = blockIdx.x;
  const float* W;
  bf16* Wt;
  int K, N, tile, tilesX;
  if (id < 2304) {
    int w = id / 576;
    tile = id - w * 576;
    W = (w == 0) ? Wq_l : (w == 1) ? Wk_l : (w == 2) ? Wv_l : Wo_l;
    Wt = wt + (size_t)w * Hn * Hn;
    K = Hn; N = Hn; tilesX = Hn / 32;
  } else if (id < 4608) {
    tile = id - 2304;
    W = W1_l;
    Wt = wt + 4 * (size_t)Hn * Hn;
    K = Hn; N = FFn; tilesX = FFn / 32;
  } else {
    tile = id - 4608;
    W = W2_l;
    Wt = wt + 4 * (size_t)Hn * Hn + (size_t)Hn * FFn;
    K = FFn; N = Hn; tilesX = Hn / 32;
  }
  int n0 = (tile % tilesX) * 32, k0 = (tile / tilesX) * 32;

  __shared__ float t[32][33];
  int tx = threadIdx.x & 31, ty = threadIdx.x >> 5;
#pragma unroll
  for (int i = 0; i < 32; i += 8)
    t[ty + i][tx] = W[(long)(k0 + ty + i) * N + n0 + tx];
  __syncthreads();
#pragma unroll
  for (int i = 0; i < 32; i += 8)
    stc(Wt + (long)(n0 + ty + i) * K + k0 + tx, t[tx][ty + i]);
}

// ---------------------------------------------------------------------------
// LayerNorm
// ---------------------------------------------------------------------------
__global__ void __launch_bounds__(256) ln_kernel(
    const float* __restrict__ x, const float* __restrict__ g,
    const float* __restrict__ b, bf16* __restrict__ out) {
  long token = blockIdx.x;
  const float* xr = x + token * Hn;
  bf16* orow = out + token * Hn;
  int tid = threadIdx.x;

  float vals[3];
  float s1 = 0.f;
#pragma unroll
  for (int i = 0; i < 3; i++) {
    vals[i] = xr[tid + 256 * i];
    s1 += vals[i];
  }
  __shared__ float sb[4];
  __shared__ float stat[2];
#pragma unroll
  for (int off = 32; off > 0; off >>= 1) s1 += __shfl_down(s1, off, 64);
  if ((tid & 63) == 0) sb[tid >> 6] = s1;
  __syncthreads();
  if (tid == 0) stat[0] = (sb[0] + sb[1] + sb[2] + sb[3]) * (1.0f / Hn);
  __syncthreads();
  float mean = stat[0];

  float s2 = 0.f;
#pragma unroll
  for (int i = 0; i < 3; i++) {
    float d = vals[i] - mean;
    s2 += d * d;
  }
#pragma unroll
  for (int off = 32; off > 0; off >>= 1) s2 += __shfl_down(s2, off, 64);
  if ((tid & 63) == 0) sb[tid >> 6] = s2;
  __syncthreads();
  if (tid == 0)
    stat[1] = rsqrtf((sb[0] + sb[1] + sb[2] + sb[3]) * (1.0f / Hn) + LN_EPS);
  __syncthreads();
  float inv = stat[1];

#pragma unroll
  for (int i = 0; i < 3; i++) {
    int d = tid + 256 * i;
    stc(orow + d, (vals[i] - mean) * inv * g[d] + b[d]);
  }
}

// ---------------------------------------------------------------------------
// 256x256 8-phase MFMA GEMM (T2+T3+T4+T5), strength-reduced addressing.
//   LDS layout (bytes): A0@0, A1@32768, B0@65536, B1@98304  (128 KiB)
//   Buffer select = +32768 immediate in ds_read offset; 4 hoisted per-lane
//   read bases; global stage sources = per-lane base + uniform offset,
//   bumped +128 elems per tile pair.  Main loop unrolled x2, tail peeled.
//   EPI: 1 = bias+res (f32 out), 2 = gelu(bias) (bf16), 4 = fused QKV.
//   Assumes M%256==0, N%256==0, K%128==0, K>=256, grid%8==0.
// ---------------------------------------------------------------------------
template <int EPI, typename CT>
__global__ void __launch_bounds__(512) gemm256_kernel(
    const bf16* __restrict__ A, const bf16* __restrict__ Bt,
    const float* __restrict__ bias, const float* __restrict__ res,
    CT* __restrict__ C, int M, int N, int K,
    const float* __restrict__ bias2, const float* __restrict__ bias3) {
  __shared__ short lds[65536];
  int tid = threadIdx.x;
  int wave = tid >> 6, lane = tid & 63;
  int wm = wave >> 2, wn = wave & 3;   // 2 x 4 wave grid
  int quad = lane >> 4, l16 = lane & 15;
  int swz = (l16 & 7) << 4;            // read-side XOR (bytes)
  int g = lane >> 3;                   // staging row within 8-row chunk
  int kswz = ((lane & 7) ^ g) * 8;     // staging pre-swizzled k-offset (elems)

  // bijective XCD-chunked swizzle (grid%8==0 for all our launches)
  int nwg = gridDim.x, orig = blockIdx.x;
  int q8 = nwg >> 3, r8 = nwg & 7;
  int xcd = orig & 7, loc = orig >> 3;
  int wg = (xcd < r8 ? xcd * (q8 + 1) : r8 * (q8 + 1) + (xcd - r8) * q8) + loc;
  int gx = N >> 8;
  long colBase = (long)(wg % gx) * 256;
  long rowBase = (long)(wg / gx) * 256;

  // per-lane global stage bases (bumped +128 elements per pair)
  const bf16* aSrc = A + rowBase * K + (long)g * K + kswz;
  const bf16* bSrc = Bt + colBase * K + (long)g * K + kswz;

  // wave-uniform row groups: r0 = row of 8-row chunk; s = element offset in src
  int r0A[2][2], r0B[2][2], sA[2][2], sB[2][2];
#pragma unroll
  for (int o = 0; o < 2; o++)
#pragma unroll
    for (int j = 0; j < 2; j++) {
      int c = wave * 2 + j;
      r0A[o][j] = o * 64 + ((c >> 3) << 7) + ((c & 7) << 3);
      r0B[o][j] = o * 32 + ((c >> 2) << 6) + ((c & 3) << 3);
      sA[o][j] = r0A[o][j] * K;
      sB[o][j] = r0B[o][j] * K;
    }

  // hoisted per-lane LDS read bases (buffer select is an immediate)
  char* lb = (char*)lds;
  const char* aRd0 = lb + (wm * 128 + l16) * 128 + ((quad * 16) ^ swz);
  const char* aRd1 = lb + (wm * 128 + l16) * 128 + ((64 + quad * 16) ^ swz);
  const char* bRd0 = lb + 65536 + (wn * 64 + l16) * 128 + ((quad * 16) ^ swz);
  const char* bRd1 = lb + 65536 + (wn * 64 + l16) * 128 + ((64 + quad * 16) ^ swz);

  f32x4 acc[8][4] = {};
  bf16x8 af[4][2], bfr[2][2][2];

#define STAGEA(ODD, BUF, KOFF)                                              \
  {                                                                         \
    gld16(aSrc + sA[ODD][0] + (KOFF),                                       \
          (short*)(lb + (BUF) * 32768 + r0A[ODD][0] * 128));                \
    gld16(aSrc + sA[ODD][1] + (KOFF),                                       \
          (short*)(lb + (BUF) * 32768 + r0A[ODD][1] * 128));                \
  }
#define STAGEB(ODD, BUF, KOFF)                                              \
  {                                                                         \
    gld16(bSrc + sB[ODD][0] + (KOFF),                                       \
          (short*)(lb + 65536 + (BUF) * 32768 + r0B[ODD][0] * 128));        \
    gld16(bSrc + sB[ODD][1] + (KOFF),                                       \
          (short*)(lb + 65536 + (BUF) * 32768 + r0B[ODD][1] * 128));        \
  }
#define LOADA(BUF, H)                                                       \
  {                                                                         \
    _Pragma("unroll") for (int i_ = 0; i_ < 4; i_++) {                      \
      af[i_][0] = *(const bf16x8*)(aRd0 + (BUF) * 32768 +                   \
                                   ((H) * 64 + i_ * 16) * 128);             \
      af[i_][1] = *(const bf16x8*)(aRd1 + (BUF) * 32768 +                   \
                                   ((H) * 64 + i_ * 16) * 128);             \
    }                                                                       \
  }
#define LOADB(BUF, NH)                                                      \
  {                                                                         \
    _Pragma("unroll") for (int j_ = 0; j_ < 2; j_++) {                      \
      bfr[NH][j_][0] = *(const bf16x8*)(bRd0 + (BUF) * 32768 +              \
                                        ((NH) * 32 + j_ * 16) * 128);       \
      bfr[NH][j_][1] = *(const bf16x8*)(bRd1 + (BUF) * 32768 +              \
                                        ((NH) * 32 + j_ * 16) * 128);       \
    }                                                                       \
  }
#define MFMA_PH(h, nh)                                                      \
  __builtin_amdgcn_s_setprio(1);                                            \
  _Pragma("unroll") for (int i_ = 0; i_ < 4; i_++)                          \
      _Pragma("unroll") for (int j_ = 0; j_ < 2; j_++)                      \
          _Pragma("unroll") for (int s_ = 0; s_ < 2; s_++)                  \
              acc[(h) * 4 + i_][(nh) * 2 + j_] =                            \
                  __builtin_amdgcn_mfma_f32_16x16x32_bf16(                  \
                      af[i_][s_], bfr[nh][j_][s_],                          \
                      acc[(h) * 4 + i_][(nh) * 2 + j_], 0, 0, 0);           \
  __builtin_amdgcn_s_setprio(0);

  int NT = K >> 6;
  // prologue: tile0 complete (buf0) + tile1 A-even,B-even,B-odd (buf1)
  STAGEA(0, 0, 0); STAGEB(0, 0, 0); STAGEB(1, 0, 0); STAGEA(1, 0, 0);
  STAGEA(0, 1, 64); STAGEB(0, 1, 64); STAGEB(1, 1, 64);
  VMC(6);   // tile0 fully landed; tile1's 3 half-tiles in flight
  BAR();

  int pairs = (NT - 2) >> 1;   // full pairs; tail pair peeled
  for (int p = 0; p < pairs; p++) {
    // ---- tile E (buf0); stages: E+1.H3(A-odd,buf1,+64), E+2.{A-even,B-even,B-odd}(buf0,+128)
    LOADA(0, 0); LOADB(0, 0); STAGEA(1, 1, 64);
    BAR(); LGKM0(); MFMA_PH(0, 0); BAR();
    LOADB(0, 1); STAGEA(0, 0, 128);
    BAR(); LGKM0(); MFMA_PH(0, 1); BAR();
    LOADA(0, 1); STAGEB(0, 0, 128);
    BAR(); LGKM0(); MFMA_PH(1, 1); BAR();
    STAGEB(1, 0, 128); VMC(6);
    BAR(); MFMA_PH(1, 0); BAR();
    // ---- tile O (buf1); stages: E+2.H3(A-odd,buf0,+128), E+3.{...}(buf1,+192)
    LOADA(1, 0); LOADB(1, 0); STAGEA(1, 0, 128);
    BAR(); LGKM0(); MFMA_PH(0, 0); BAR();
    LOADB(1, 1); STAGEA(0, 1, 192);
    BAR(); LGKM0(); MFMA_PH(0, 1); BAR();
    LOADA(1, 1); STAGEB(0, 1, 192);
    BAR(); LGKM0(); MFMA_PH(1, 1); BAR();
    STAGEB(1, 1, 192); VMC(6);
    BAR(); MFMA_PH(1, 0); BAR();
    aSrc += 128; bSrc += 128;
  }
  // ---- tail pair: tiles NT-2 (buf0) and NT-1 (buf1)
  LOADA(0, 0); LOADB(0, 0); STAGEA(1, 1, 64);
  BAR(); LGKM0(); MFMA_PH(0, 0); BAR();
  LOADB(0, 1);
  BAR(); LGKM0(); MFMA_PH(0, 1); BAR();
  LOADA(0, 1);
  BAR(); LGKM0(); MFMA_PH(1, 1); BAR();
  VMC(0);
  BAR(); MFMA_PH(1, 0); BAR();
  LOADA(1, 0); LOADB(1, 0);
  BAR(); LGKM0(); MFMA_PH(0, 0); BAR();
  LOADB(1, 1);
  BAR(); LGKM0(); MFMA_PH(0, 1); BAR();
  LOADA(1, 1);
  BAR(); LGKM0(); MFMA_PH(1, 1); BAR();
  BAR(); MFMA_PH(1, 0); BAR();

  // epilogue: D col=lane&15, row=quad*4+reg
#pragma unroll
  for (int mi = 0; mi < 8; mi++) {
#pragma unroll
    for (int nj = 0; nj < 4; nj++) {
      int col = (int)colBase + wn * 64 + nj * 16 + l16;
      long row0 = rowBase + wm * 128 + mi * 16 + quad * 4;
      if (EPI == 4) {
        if (col < 1536) {
          float bv = col < 768 ? bias[col] : bias2[col - 768];
          bf16* dst = (bf16*)C + (col < 768 ? 0 : (size_t)BSn * Hn - Hn);
#pragma unroll
          for (int r = 0; r < 4; r++)
            stc(dst + (row0 + r) * Hn + col, acc[mi][nj][r] + bv);
        } else {
          int vcol = col - 1536;
          float bv = bias3[vcol];
          union { uint2 w; bf16 h[4]; } pk;
          long bb = row0 >> 11;          // token / Sn
          long s = row0 & (Sn - 1);      // token % Sn
#pragma unroll
          for (int r = 0; r < 4; r++)
            pk.h[r] = __float2bfloat16(acc[mi][nj][r] + bv);
          bf16* vT = (bf16*)C + 2 * (size_t)BSn * Hn;
          *reinterpret_cast<uint2*>(vT + (bb * Hn + vcol) * Sn + s) = pk.w;
        }
      } else {
        float bv = bias[col];
#pragma unroll
        for (int r = 0; r < 4; r++) {
          long row = row0 + r;
          float v = acc[mi][nj][r] + bv;
          if (EPI == 1) v += res[row * N + col];
          if (EPI == 2) v = gelu_exact(v);
          stc(C + row * N + col, v);
        }
      }
    }
  }
#undef STAGEA
#undef STAGEB
#undef LOADA
#undef LOADB
#undef MFMA_PH
}

// ---------------------------------------------------------------------------
// QK^T via MFMA (128x128, causal early-out)
// ---------------------------------------------------------------------------
__global__ void __launch_bounds__(256) qk_mfma_kernel(
    const bf16* __restrict__ q, const bf16* __restrict__ k,
    bf16* __restrict__ sc, int q0) {
  int kBase = blockIdx.x * 128;
  int qBase = q0 + blockIdx.y * 128;
  if (kBase > qBase + 127) return;
  int b = blockIdx.z;
  const bf16* Ag = q + ((long)b * Sn + qBase) * Hn;
  const bf16* Bg = k + ((long)b * Sn + kBase) * Hn;

  __shared__ short As[128 * 32];
  __shared__ short Bs[128 * 32];
  int tid = threadIdx.x;
  int wave = tid >> 6, lane = tid & 63;
  int waveM = wave >> 1, waveN = wave & 1;
  int quad = lane >> 4, l16 = lane & 15;
  int srow = lane >> 2;
  int schunk = (lane & 3) * 8;

  f32x4 acc[4][4] = {};

  for (int kt = 0; kt < Hn; kt += 32) {
#pragma unroll
    for (int c = 0; c < 2; c++) {
      int r0 = wave * 32 + c * 16;
      gld16(Ag + (long)(r0 + srow) * Hn + kt + schunk, &As[r0 * 32]);
      gld16(Bg + (long)(r0 + srow) * Hn + kt + schunk, &Bs[r0 * 32]);
    }
    __syncthreads();

    bf16x8 af[4], bfrg[4];
#pragma unroll
    for (int t = 0; t < 4; t++)
      af[t] = *(const bf16x8*)&As[(waveM * 64 + t * 16 + l16) * 32 + quad * 8];
#pragma unroll
    for (int u = 0; u < 4; u++)
      bfrg[u] = *(const bf16x8*)&Bs[(waveN * 64 + u * 16 + l16) * 32 + quad * 8];
#pragma unroll
    for (int t = 0; t < 4; t++)
#pragma unroll
      for (int u = 0; u < 4; u++)
        acc[t][u] = __builtin_amdgcn_mfma_f32_16x16x32_bf16(af[t], bfrg[u],
                                                            acc[t][u], 0, 0, 0);
    __syncthreads();
  }

  const float scale = 0.03608439182435161f;  // 1/sqrt(768)
#pragma unroll
  for (int t = 0; t < 4; t++)
#pragma unroll
    for (int u = 0; u < 4; u++) {
      int col = kBase + waveN * 64 + u * 16 + l16;
#pragma unroll
      for (int r = 0; r < 4; r++) {
        long qRel = (long)(qBase - q0) + waveM * 64 + t * 16 + quad * 4 + r;
        stc(sc + ((long)b * CQ + qRel) * Sn + col, acc[t][u][r] * scale);
      }
    }
}

// ---------------------------------------------------------------------------
// P @ V via MFMA (128x128; vT operand; causal K-limit)
// ---------------------------------------------------------------------------
__global__ void __launch_bounds__(256) pv_mfma_kernel(
    const bf16* __restrict__ p, const bf16* __restrict__ vT,
    bf16* __restrict__ o, int q0) {
  int colBase = blockIdx.x * 128;
  int qBase = q0 + blockIdx.y * 128;
  int b = blockIdx.z;
  int klimit = qBase + 128;
  const bf16* Ag = p + ((long)b * CQ + (qBase - q0)) * Sn;
  const bf16* Bg = vT + ((long)b * Hn + colBase) * Sn;

  __shared__ short As[128 * 32];
  __shared__ short Bs[128 * 32];
  int tid = threadIdx.x;
  int wave = tid >> 6, lane = tid & 63;
  int waveM = wave >> 1, waveN = wave & 1;
  int quad = lane >> 4, l16 = lane & 15;
  int srow = lane >> 2;
  int schunk = (lane & 3) * 8;

  f32x4 acc[4][4] = {};

  for (int kt = 0; kt < klimit; kt += 32) {
#pragma unroll
    for (int c = 0; c < 2; c++) {
      int r0 = wave * 32 + c * 16;
      gld16(Ag + (long)(r0 + srow) * Sn + kt + schunk, &As[r0 * 32]);
      gld16(Bg + (long)(r0 + srow) * Sn + kt + schunk, &Bs[r0 * 32]);
    }
    __syncthreads();

    bf16x8 af[4], bfrg[4];
#pragma unroll
    for (int t = 0; t < 4; t++)
      af[t] = *(const bf16x8*)&As[(waveM * 64 + t * 16 + l16) * 32 + quad * 8];
#pragma unroll
    for (int u = 0; u < 4; u++)
      bfrg[u] = *(const bf16x8*)&Bs[(waveN * 64 + u * 16 + l16) * 32 + quad * 8];
#pragma unroll
    for (int t = 0; t < 4; t++)
#pragma unroll
      for (int u = 0; u < 4; u++)
        acc[t][u] = __builtin_amdgcn_mfma_f32_16x16x32_bf16(af[t], bfrg[u],
                                                            acc[t][u], 0, 0, 0);
    __syncthreads();
  }

#pragma unroll
  for (int t = 0; t < 4; t++)
#pragma unroll
    for (int u = 0; u < 4; u++) {
      int col = colBase + waveN * 64 + u * 16 + l16;
#pragma unroll
      for (int r = 0; r < 4; r++) {
        long qAbs = (long)qBase + waveM * 64 + t * 16 + quad * 4 + r;
        stc(o + ((long)b * Sn + qAbs) * Hn + col, acc[t][u][r]);
      }
    }
}

// ---------------------------------------------------------------------------
// Softmax (vectorized bf16x8); zero-fills to 128-aligned limit for PV.
// ---------------------------------------------------------------------------
__global__ void __launch_bounds__(256) softmax_kernel(
    bf16* __restrict__ sc, const int* __restrict__ mask, int q0) {
  int qRel = blockIdx.x;
  int b = blockIdx.y;
  int qg = q0 + qRel;
  bf16* row = sc + ((long)b * CQ + qRel) * Sn;
  const int* mrow = mask + b * Sn;
  int tid = threadIdx.x;
  int n = qg + 1;
  int limit = (qg & ~127) + 128;
  int k0 = tid * 8;

  Pk8 pk;
  pk.v = *reinterpret_cast<const float4*>(row + k0);
  int4 m0 = *reinterpret_cast<const int4*>(mrow + k0);
  int4 m1 = *reinterpret_cast<const int4*>(mrow + k0 + 4);
  int mm[8] = {m0.x, m0.y, m0.z, m0.w, m1.x, m1.y, m1.z, m1.w};

  float sv[8];
  float lmax = -1e30f;
#pragma unroll
  for (int j = 0; j < 8; j++) {
    int kk = k0 + j;
    float s = (kk < n && mm[j] != 0) ? b2f(pk.h[j]) : -1e30f;
    sv[j] = s;
    lmax = fmaxf(lmax, s);
  }
  __shared__ float sb[4];
  __shared__ float stat;
#pragma unroll
  for (int off = 32; off > 0; off >>= 1)
    lmax = fmaxf(lmax, __shfl_down(lmax, off, 64));
  if ((tid & 63) == 0) sb[tid >> 6] = lmax;
  __syncthreads();
  if (tid == 0) stat = fmaxf(fmaxf(sb[0], sb[1]), fmaxf(sb[2], sb[3]));
  __syncthreads();
  float gmax = stat;

  float ev[8];
  float lsum = 0.f;
#pragma unroll
  for (int j = 0; j < 8; j++) {
    float e = (sv[j] > -1e29f) ? __expf(sv[j] - gmax) : 0.f;
    ev[j] = e;
    lsum += e;
  }
#pragma unroll
  for (int off = 32; off > 0; off >>= 1) lsum += __shfl_down(lsum, off, 64);
  if ((tid & 63) == 0) sb[tid >> 6] = lsum;
  __syncthreads();
  if (tid == 0) stat = sb[0] + sb[1] + sb[2] + sb[3];
  __syncthreads();
  float inv = 1.0f / stat;

  if (k0 < limit) {
    Pk8 o;
#pragma unroll
    for (int j = 0; j < 8; j++)
      o.h[j] = __float2bfloat16((k0 + j < n) ? ev[j] * inv : 0.f);
    *reinterpret_cast<float4*>(row + k0) = o.v;
  }
}

// ---------------------------------------------------------------------------
// Classifier head
// ---------------------------------------------------------------------------
__global__ void __launch_bounds__(256) cls_kernel(
    const bf16* __restrict__ h, const int* __restrict__ mask,
    const float* __restrict__ clsW, const float* __restrict__ clsb,
    float* __restrict__ out) {
  int b = blockIdx.x;
  int tid = threadIdx.x;
  __shared__ float sb[4];
  __shared__ int ib[4];
  __shared__ int lastsh;

  int ls = 0;
  for (int s = tid; s < Sn; s += 256) ls += mask[b * Sn + s];
#pragma unroll
  for (int off = 32; off > 0; off >>= 1) ls += __shfl_down(ls, off, 64);
  if ((tid & 63) == 0) ib[tid >> 6] = ls;
  __syncthreads();
  if (tid == 0) lastsh = ib[0] + ib[1] + ib[2] + ib[3] - 1;
  __syncthreads();
  int last = lastsh;

  const bf16* row = h + ((long)b * Sn + last) * Hn;
  float acc = 0.f;
  for (int d = tid; d < Hn; d += 256) acc += b2f(row[d]) * clsW[d];
#pragma unroll
  for (int off = 32; off > 0; off >>= 1) acc += __shfl_down(acc, off, 64);
  if ((tid & 63) == 0) sb[tid >> 6] = acc;
  __syncthreads();
  if (tid == 0) out[b] = sb[0] + sb[1] + sb[2] + sb[3] + clsb[0];
}

// ---------------------------------------------------------------------------
// Orchestration
// ---------------------------------------------------------------------------
extern "C" void kernel_launch(void* const* d_in, const int* in_sizes, int n_in,
                              void* d_out, int out_size, void* d_ws,
                              size_t ws_size, hipStream_t stream) {
  const int* ids     = (const int*)d_in[0];
  const int* mask    = (const int*)d_in[1];
  const float* tok   = (const float*)d_in[2];
  const float* pos   = (const float*)d_in[3];
  const float* Wq    = (const float*)d_in[4];
  const float* bq    = (const float*)d_in[5];
  const float* Wk    = (const float*)d_in[6];
  const float* bk    = (const float*)d_in[7];
  const float* Wv    = (const float*)d_in[8];
  const float* bv    = (const float*)d_in[9];
  const float* Wo    = (const float*)d_in[10];
  const float* bo    = (const float*)d_in[11];
  const float* ln1g  = (const float*)d_in[12];
  const float* ln1b  = (const float*)d_in[13];
  const float* ln2g  = (const float*)d_in[14];
  const float* ln2b  = (const float*)d_in[15];
  const float* W1    = (const float*)d_in[16];
  const float* b1    = (const float*)d_in[17];
  const float* W2    = (const float*)d_in[18];
  const float* b2    = (const float*)d_in[19];
  const float* flng  = (const float*)d_in[20];
  const float* flnb  = (const float*)d_in[21];
  const float* clsW  = (const float*)d_in[22];
  const float* clsb  = (const float*)d_in[23];

  float* x = (float*)d_ws;
  bf16* h  = (bf16*)(x + (size_t)BSn * Hn);
  bf16* cb = h + (size_t)BSn * Hn;
  bf16* qb = cb;                          // [BSn][Hn]
  bf16* kb = cb + (size_t)BSn * Hn;       // [BSn][Hn]
  bf16* vtb = cb + 2 * (size_t)BSn * Hn;  // V^T [Bn][Hn][Sn]
  bf16* scb = cb + 3 * (size_t)BSn * Hn;  // [Bn, CQ, Sn]
  bf16* wt = cb + (size_t)BSn * FFn;
  bf16* wqT = wt;                                   // wq,wk,wv contiguous
  bf16* woT = wqT + 3 * (size_t)Hn * Hn;
  bf16* w1T = woT + (size_t)Hn * Hn;                // [FF][H]
  bf16* w2T = w1T + (size_t)Hn * FFn;               // [H][FF]

  const int M = BSn;
  dim3 blk(256);
  dim3 blk512(512);
  dim3 gridQK(Sn / 128, CQ / 128, Bn);
  dim3 gridSM(CQ, Bn);
  dim3 gridPV(Hn / 128, CQ / 128, Bn);

  embed_kernel<<<BSn, blk, 0, stream>>>(ids, tok, pos, x);

  for (int l = 0; l < Ln; l++) {
    const float* Wq_l = Wq + (size_t)l * Hn * Hn;
    const float* Wk_l = Wk + (size_t)l * Hn * Hn;
    const float* Wv_l = Wv + (size_t)l * Hn * Hn;
    const float* Wo_l = Wo + (size_t)l * Hn * Hn;
    const float* W1_l = W1 + (size_t)l * Hn * FFn;
    const float* W2_l = W2 + (size_t)l * FFn * Hn;

    transpose_all_kernel<<<6912, blk, 0, stream>>>(Wq_l, Wk_l, Wv_l, Wo_l,
                                                   W1_l, W2_l, wt);

    // --- attention block ---
    ln_kernel<<<BSn, blk, 0, stream>>>(x, ln1g + l * Hn, ln1b + l * Hn, h);
    // fused QKV (M=16384, N=2304, K=768): 576 blocks
    gemm256_kernel<4, bf16><<<576, blk512, 0, stream>>>(
        h, wqT, bq + l * Hn, nullptr, qb, M, 3 * Hn, Hn,
        bk + l * Hn, bv + l * Hn);
    for (int c = 0; c < Sn / CQ; c++) {
      int q0 = c * CQ;
      qk_mfma_kernel<<<gridQK, blk, 0, stream>>>(qb, kb, scb, q0);
      softmax_kernel<<<gridSM, blk, 0, stream>>>(scb, mask, q0);
      pv_mfma_kernel<<<gridPV, blk, 0, stream>>>(scb, vtb, h, q0);
    }
    // Wo (N=768, K=768): 192 blocks
    gemm256_kernel<1, float><<<192, blk512, 0, stream>>>(
        h, woT, bo + l * Hn, x, x, M, Hn, Hn, nullptr, nullptr);

    // --- FFN block ---
    ln_kernel<<<BSn, blk, 0, stream>>>(x, ln2g + l * Hn, ln2b + l * Hn, h);
    // W1 (N=3072, K=768): 768 blocks
    gemm256_kernel<2, bf16><<<768, blk512, 0, stream>>>(
        h, w1T, b1 + l * FFn, nullptr, cb, M, FFn, Hn, nullptr, nullptr);
    // W2 (N=768, K=3072): 192 blocks
    gemm256_kernel<1, float><<<192, blk512, 0, stream>>>(
        cb, w2T, b2 + l * Hn, x, x, M, Hn, FFn, nullptr, nullptr);
  }

  ln_kernel<<<BSn, blk, 0, stream>>>(x, flng, flnb, h);
  cls_kernel<<<Bn, blk, 0, stream>>>(h, mask, clsW, clsb, (float*)d_out);
}

// Round 6
// 3805.898 us; speedup vs baseline: 3.2211x; 1.0314x over previous
//
#include <hip/hip_runtime.h>
#include <hip/hip_bf16.h>

// Problem constants (BinaryClassifyModel: L=6, B=8, S=2048, H=768, V=32000)
#define Bn 8
#define Sn 2048
#define Hn 768
#define FFn 3072
#define Ln 6
#define BSn (Bn * Sn)       // 16384 tokens
#define CQ 512              // query chunk for attention scores buffer
#define LN_EPS 1e-5f

typedef __hip_bfloat16 bf16;
typedef __bf16 bf16x8 __attribute__((ext_vector_type(8)));
typedef float f32x4 __attribute__((ext_vector_type(4)));

__device__ __forceinline__ float b2f(bf16 v) { return __bfloat162float(v); }
__device__ __forceinline__ void stc(float* p, float v) { *p = v; }
__device__ __forceinline__ void stc(bf16* p, float v) { *p = __float2bfloat16(v); }

union Pk8 { float4 v; bf16 h[8]; };   // 8 consecutive bf16 = one 16B load

// async global->LDS, 16B per lane; LDS dest = wave-uniform base + lane*16
__device__ __forceinline__ void gld16(const bf16* g, short* l) {
  __builtin_amdgcn_global_load_lds(
      (const __attribute__((address_space(1))) unsigned int*)g,
      (__attribute__((address_space(3))) unsigned int*)l, 16, 0, 0);
}

#define BAR() __builtin_amdgcn_s_barrier()
#define VMC(n) asm volatile("s_waitcnt vmcnt(" #n ")" ::: "memory")

// exact-GELU via A&S 7.1.26 erf polynomial on v/sqrt(2), |eps| <= 1.5e-7
__device__ __forceinline__ float gelu_exact(float v) {
  float a = fabsf(v) * 0.70710678118654752f;   // |v| / sqrt(2)
  float t = 1.0f / (1.0f + 0.3275911f * a);
  float poly = t * (0.254829592f +
               t * (-0.284496736f +
               t * (1.421413741f +
               t * (-1.453152027f + t * 1.061405429f))));
  float er = 1.0f - poly * __expf(-a * a);
  er = v < 0.f ? -er : er;
  return 0.5f * v * (1.0f + er);
}

// ---------------------------------------------------------------------------
// Embedding
// ---------------------------------------------------------------------------
__global__ void __launch_bounds__(256) embed_kernel(
    const int* __restrict__ ids, const float* __restrict__ tok,
    const float* __restrict__ pos, float* __restrict__ x) {
  long t = blockIdx.x;
  int s = (int)(t & (Sn - 1));
  long id = ids[t];
  const float* tr = tok + id * Hn;
  const float* pr = pos + (long)s * Hn;
  float* xr = x + t * Hn;
  for (int d = threadIdx.x; d < Hn; d += 256)
    xr[d] = tr[d] + pr[d];
}

// ---------------------------------------------------------------------------
// All-weights transpose + cast for one layer, single launch (6912 blocks).
// ---------------------------------------------------------------------------
__global__ void __launch_bounds__(256) transpose_all_kernel(
    const float* __restrict__ Wq_l, const float* __restrict__ Wk_l,
    const float* __restrict__ Wv_l, const float* __restrict__ Wo_l,
    const float* __restrict__ W1_l, const float* __restrict__ W2_l,
    bf16* __restrict__ wt) {
  int id = blockIdx.x;
  const float* W;
  bf16* Wt;
  int K, N, tile, tilesX;
  if (id < 2304) {
    int w = id / 576;
    tile = id - w * 576;
    W = (w == 0) ? Wq_l : (w == 1) ? Wk_l : (w == 2) ? Wv_l : Wo_l;
    Wt = wt + (size_t)w * Hn * Hn;
    K = Hn; N = Hn; tilesX = Hn / 32;
  } else if (id < 4608) {
    tile = id - 2304;
    W = W1_l;
    Wt = wt + 4 * (size_t)Hn * Hn;
    K = Hn; N = FFn; tilesX = FFn / 32;
  } else {
    tile = id - 4608;
    W = W2_l;
    Wt = wt + 4 * (size_t)Hn * Hn + (size_t)Hn * FFn;
    K = FFn; N = Hn; tilesX = Hn / 32;
  }
  int n0 = (tile % tilesX) * 32, k0 = (tile / tilesX) * 32;

  __shared__ float t[32][33];
  int tx = threadIdx.x & 31, ty = threadIdx.x >> 5;
#pragma unroll
  for (int i = 0; i < 32; i += 8)
    t[ty + i][tx] = W[(long)(k0 + ty + i) * N + n0 + tx];
  __syncthreads();
#pragma unroll
  for (int i = 0; i < 32; i += 8)
    stc(Wt + (long)(n0 + ty + i) * K + k0 + tx, t[tx][ty + i]);
}

// ---------------------------------------------------------------------------
// LayerNorm
// ---------------------------------------------------------------------------
__global__ void __launch_bounds__(256) ln_kernel(
    const float* __restrict__ x, const float* __restrict__ g,
    const float* __restrict__ b, bf16* __restrict__ out) {
  long token = blockIdx.x;
  const float* xr = x + token * Hn;
  bf16* orow = out + token * Hn;
  int tid = threadIdx.x;

  float vals[3];
  float s1 = 0.f;
#pragma unroll
  for (int i = 0; i < 3; i++) {
    vals[i] = xr[tid + 256 * i];
    s1 += vals[i];
  }
  __shared__ float sb[4];
  __shared__ float stat[2];
#pragma unroll
  for (int off = 32; off > 0; off >>= 1) s1 += __shfl_down(s1, off, 64);
  if ((tid & 63) == 0) sb[tid >> 6] = s1;
  __syncthreads();
  if (tid == 0) stat[0] = (sb[0] + sb[1] + sb[2] + sb[3]) * (1.0f / Hn);
  __syncthreads();
  float mean = stat[0];

  float s2 = 0.f;
#pragma unroll
  for (int i = 0; i < 3; i++) {
    float d = vals[i] - mean;
    s2 += d * d;
  }
#pragma unroll
  for (int off = 32; off > 0; off >>= 1) s2 += __shfl_down(s2, off, 64);
  if ((tid & 63) == 0) sb[tid >> 6] = s2;
  __syncthreads();
  if (tid == 0)
    stat[1] = rsqrtf((sb[0] + sb[1] + sb[2] + sb[3]) * (1.0f / Hn) + LN_EPS);
  __syncthreads();
  float inv = stat[1];

#pragma unroll
  for (int i = 0; i < 3; i++) {
    int d = tid + 256 * i;
    stc(orow + d, (vals[i] - mean) * inv * g[d] + b[d]);
  }
}

// ---------------------------------------------------------------------------
// 256x256 MFMA GEMM — 2-barrier-per-tile free-running schedule (T1+T2+T14).
//   LDS (bytes): A0@0, A1@32768, B0@65536, B1@98304 (128 KiB, dbuf BK=64).
//   Per tile: issue all 8 global_load_lds for tile T+1 (depth-1, issue-early),
//   then ds_reads + 64 MFMAs compiler-pipelined (no intra-tile barriers, no
//   manual lgkmcnt — compiler emits counted waits), then vmcnt(0)+s_barrier.
//   Hazards: stages target buf^1, last read in tile T-1 (pre-entry barrier);
//   tile-T reads staged at T-1 and drained by T-1's vmcnt(0)+barrier.
//   EPI: 1 = bias+res (f32 out), 2 = gelu(bias) (bf16), 4 = fused QKV.
//   Assumes M%256==0, N%256==0, K%128==0, grid%8==0 (NT even, >=2).
// ---------------------------------------------------------------------------
template <int EPI, typename CT>
__global__ void __launch_bounds__(512) gemm256_kernel(
    const bf16* __restrict__ A, const bf16* __restrict__ Bt,
    const float* __restrict__ bias, const float* __restrict__ res,
    CT* __restrict__ C, int M, int N, int K,
    const float* __restrict__ bias2, const float* __restrict__ bias3) {
  __shared__ short lds[65536];
  int tid = threadIdx.x;
  int wave = tid >> 6, lane = tid & 63;
  int wm = wave >> 2, wn = wave & 3;   // 2 x 4 wave grid
  int quad = lane >> 4, l16 = lane & 15;
  int swz = (l16 & 7) << 4;            // read-side XOR (bytes)
  int g = lane >> 3;                   // staging row within 8-row chunk
  int kswz = ((lane & 7) ^ g) * 8;     // staging pre-swizzled k-offset (elems)

  // bijective XCD-chunked swizzle (grid%8==0 for all our launches)
  int nwg = gridDim.x, orig = blockIdx.x;
  int q8 = nwg >> 3, r8 = nwg & 7;
  int xcd = orig & 7, loc = orig >> 3;
  int wg = (xcd < r8 ? xcd * (q8 + 1) : r8 * (q8 + 1) + (xcd - r8) * q8) + loc;
  int gx = N >> 8;
  long colBase = (long)(wg % gx) * 256;
  long rowBase = (long)(wg / gx) * 256;

  // per-lane global stage bases (bumped +128 elements per tile pair)
  const bf16* aSrc = A + rowBase * K + (long)g * K + kswz;
  const bf16* bSrc = Bt + colBase * K + (long)g * K + kswz;

  // wave-uniform row groups: r0 = row of 8-row chunk; s = element offset in src
  int r0A[2][2], r0B[2][2], sA[2][2], sB[2][2];
#pragma unroll
  for (int o = 0; o < 2; o++)
#pragma unroll
    for (int j = 0; j < 2; j++) {
      int c = wave * 2 + j;
      r0A[o][j] = o * 64 + ((c >> 3) << 7) + ((c & 7) << 3);
      r0B[o][j] = o * 32 + ((c >> 2) << 6) + ((c & 3) << 3);
      sA[o][j] = r0A[o][j] * K;
      sB[o][j] = r0B[o][j] * K;
    }

  // hoisted per-lane LDS read bases (buffer select is an immediate)
  char* lb = (char*)lds;
  const char* aRd0 = lb + (wm * 128 + l16) * 128 + ((quad * 16) ^ swz);
  const char* aRd1 = lb + (wm * 128 + l16) * 128 + ((64 + quad * 16) ^ swz);
  const char* bRd0 = lb + 65536 + (wn * 64 + l16) * 128 + ((quad * 16) ^ swz);
  const char* bRd1 = lb + 65536 + (wn * 64 + l16) * 128 + ((64 + quad * 16) ^ swz);

  f32x4 acc[8][4] = {};
  bf16x8 af[4][2], bfr[2][2][2];

#define STAGEA(ODD, BUF, KOFF)                                              \
  {                                                                         \
    gld16(aSrc + sA[ODD][0] + (KOFF),                                       \
          (short*)(lb + (BUF) * 32768 + r0A[ODD][0] * 128));                \
    gld16(aSrc + sA[ODD][1] + (KOFF),                                       \
          (short*)(lb + (BUF) * 32768 + r0A[ODD][1] * 128));                \
  }
#define STAGEB(ODD, BUF, KOFF)                                              \
  {                                                                         \
    gld16(bSrc + sB[ODD][0] + (KOFF),                                       \
          (short*)(lb + 65536 + (BUF) * 32768 + r0B[ODD][0] * 128));        \
    gld16(bSrc + sB[ODD][1] + (KOFF),                                       \
          (short*)(lb + 65536 + (BUF) * 32768 + r0B[ODD][1] * 128));        \
  }
#define STAGE_ALL(BUF, KOFF)                                                \
  {                                                                         \
    STAGEA(0, BUF, KOFF); STAGEB(0, BUF, KOFF);                             \
    STAGEA(1, BUF, KOFF); STAGEB(1, BUF, KOFF);                             \
  }
#define LOADA(BUF, H)                                                       \
  {                                                                         \
    _Pragma("unroll") for (int i_ = 0; i_ < 4; i_++) {                      \
      af[i_][0] = *(const bf16x8*)(aRd0 + (BUF) * 32768 +                   \
                                   ((H) * 64 + i_ * 16) * 128);             \
      af[i_][1] = *(const bf16x8*)(aRd1 + (BUF) * 32768 +                   \
                                   ((H) * 64 + i_ * 16) * 128);             \
    }                                                                       \
  }
#define LOADB(BUF, NH)                                                      \
  {                                                                         \
    _Pragma("unroll") for (int j_ = 0; j_ < 2; j_++) {                      \
      bfr[NH][j_][0] = *(const bf16x8*)(bRd0 + (BUF) * 32768 +              \
                                        ((NH) * 32 + j_ * 16) * 128);       \
      bfr[NH][j_][1] = *(const bf16x8*)(bRd1 + (BUF) * 32768 +              \
                                        ((NH) * 32 + j_ * 16) * 128);       \
    }                                                                       \
  }
#define MFMA_PH(h, nh)                                                      \
  __builtin_amdgcn_s_setprio(1);                                            \
  _Pragma("unroll") for (int i_ = 0; i_ < 4; i_++)                          \
      _Pragma("unroll") for (int j_ = 0; j_ < 2; j_++)                      \
          _Pragma("unroll") for (int s_ = 0; s_ < 2; s_++)                  \
              acc[(h) * 4 + i_][(nh) * 2 + j_] =                            \
                  __builtin_amdgcn_mfma_f32_16x16x32_bf16(                  \
                      af[i_][s_], bfr[nh][j_][s_],                          \
                      acc[(h) * 4 + i_][(nh) * 2 + j_], 0, 0, 0);           \
  __builtin_amdgcn_s_setprio(0);
// COMPUTE: B both halves first, A h=0, two clusters, A h=1 (reg reuse),
// two clusters.  No barriers; compiler pipelines ds_reads vs MFMAs.
#define COMPUTE(BUF)                                                        \
  {                                                                         \
    LOADB(BUF, 0); LOADB(BUF, 1); LOADA(BUF, 0);                            \
    MFMA_PH(0, 0); MFMA_PH(0, 1);                                           \
    LOADA(BUF, 1);                                                          \
    MFMA_PH(1, 1); MFMA_PH(1, 0);                                           \
  }

  int NT = K >> 6;   // even, >= 2
  STAGE_ALL(0, 0);   // tile 0 -> buf0
  VMC(0); BAR();

  for (int T = 0; T < NT; T += 2) {
    STAGE_ALL(1, 64);                    // tile T+1 -> buf1 (issue-early)
    COMPUTE(0);                          // tile T from buf0
    VMC(0); BAR();
    if (T + 2 < NT) STAGE_ALL(0, 128);   // tile T+2 -> buf0
    COMPUTE(1);                          // tile T+1 from buf1
    VMC(0); BAR();
    aSrc += 128; bSrc += 128;
  }

  // epilogue: D col=lane&15, row=quad*4+reg
#pragma unroll
  for (int mi = 0; mi < 8; mi++) {
#pragma unroll
    for (int nj = 0; nj < 4; nj++) {
      int col = (int)colBase + wn * 64 + nj * 16 + l16;
      long row0 = rowBase + wm * 128 + mi * 16 + quad * 4;
      if (EPI == 4) {
        if (col < 1536) {
          float bv = col < 768 ? bias[col] : bias2[col - 768];
          bf16* dst = (bf16*)C + (col < 768 ? 0 : (size_t)BSn * Hn - Hn);
#pragma unroll
          for (int r = 0; r < 4; r++)
            stc(dst + (row0 + r) * Hn + col, acc[mi][nj][r] + bv);
        } else {
          int vcol = col - 1536;
          float bv = bias3[vcol];
          union { uint2 w; bf16 h[4]; } pk;
          long bb = row0 >> 11;          // token / Sn
          long s = row0 & (Sn - 1);      // token % Sn
#pragma unroll
          for (int r = 0; r < 4; r++)
            pk.h[r] = __float2bfloat16(acc[mi][nj][r] + bv);
          bf16* vT = (bf16*)C + 2 * (size_t)BSn * Hn;
          *reinterpret_cast<uint2*>(vT + (bb * Hn + vcol) * Sn + s) = pk.w;
        }
      } else {
        float bv = bias[col];
#pragma unroll
        for (int r = 0; r < 4; r++) {
          long row = row0 + r;
          float v = acc[mi][nj][r] + bv;
          if (EPI == 1) v += res[row * N + col];
          if (EPI == 2) v = gelu_exact(v);
          stc(C + row * N + col, v);
        }
      }
    }
  }
#undef STAGEA
#undef STAGEB
#undef STAGE_ALL
#undef LOADA
#undef LOADB
#undef MFMA_PH
#undef COMPUTE
}

// ---------------------------------------------------------------------------
// QK^T via MFMA (128x128, causal early-out)
// ---------------------------------------------------------------------------
__global__ void __launch_bounds__(256) qk_mfma_kernel(
    const bf16* __restrict__ q, const bf16* __restrict__ k,
    bf16* __restrict__ sc, int q0) {
  int kBase = blockIdx.x * 128;
  int qBase = q0 + blockIdx.y * 128;
  if (kBase > qBase + 127) return;
  int b = blockIdx.z;
  const bf16* Ag = q + ((long)b * Sn + qBase) * Hn;
  const bf16* Bg = k + ((long)b * Sn + kBase) * Hn;

  __shared__ short As[128 * 32];
  __shared__ short Bs[128 * 32];
  int tid = threadIdx.x;
  int wave = tid >> 6, lane = tid & 63;
  int waveM = wave >> 1, waveN = wave & 1;
  int quad = lane >> 4, l16 = lane & 15;
  int srow = lane >> 2;
  int schunk = (lane & 3) * 8;

  f32x4 acc[4][4] = {};

  for (int kt = 0; kt < Hn; kt += 32) {
#pragma unroll
    for (int c = 0; c < 2; c++) {
      int r0 = wave * 32 + c * 16;
      gld16(Ag + (long)(r0 + srow) * Hn + kt + schunk, &As[r0 * 32]);
      gld16(Bg + (long)(r0 + srow) * Hn + kt + schunk, &Bs[r0 * 32]);
    }
    __syncthreads();

    bf16x8 af[4], bfrg[4];
#pragma unroll
    for (int t = 0; t < 4; t++)
      af[t] = *(const bf16x8*)&As[(waveM * 64 + t * 16 + l16) * 32 + quad * 8];
#pragma unroll
    for (int u = 0; u < 4; u++)
      bfrg[u] = *(const bf16x8*)&Bs[(waveN * 64 + u * 16 + l16) * 32 + quad * 8];
#pragma unroll
    for (int t = 0; t < 4; t++)
#pragma unroll
      for (int u = 0; u < 4; u++)
        acc[t][u] = __builtin_amdgcn_mfma_f32_16x16x32_bf16(af[t], bfrg[u],
                                                            acc[t][u], 0, 0, 0);
    __syncthreads();
  }

  const float scale = 0.03608439182435161f;  // 1/sqrt(768)
#pragma unroll
  for (int t = 0; t < 4; t++)
#pragma unroll
    for (int u = 0; u < 4; u++) {
      int col = kBase + waveN * 64 + u * 16 + l16;
#pragma unroll
      for (int r = 0; r < 4; r++) {
        long qRel = (long)(qBase - q0) + waveM * 64 + t * 16 + quad * 4 + r;
        stc(sc + ((long)b * CQ + qRel) * Sn + col, acc[t][u][r] * scale);
      }
    }
}

// ---------------------------------------------------------------------------
// P @ V via MFMA (128x128; vT operand; causal K-limit)
// ---------------------------------------------------------------------------
__global__ void __launch_bounds__(256) pv_mfma_kernel(
    const bf16* __restrict__ p, const bf16* __restrict__ vT,
    bf16* __restrict__ o, int q0) {
  int colBase = blockIdx.x * 128;
  int qBase = q0 + blockIdx.y * 128;
  int b = blockIdx.z;
  int klimit = qBase + 128;
  const bf16* Ag = p + ((long)b * CQ + (qBase - q0)) * Sn;
  const bf16* Bg = vT + ((long)b * Hn + colBase) * Sn;

  __shared__ short As[128 * 32];
  __shared__ short Bs[128 * 32];
  int tid = threadIdx.x;
  int wave = tid >> 6, lane = tid & 63;
  int waveM = wave >> 1, waveN = wave & 1;
  int quad = lane >> 4, l16 = lane & 15;
  int srow = lane >> 2;
  int schunk = (lane & 3) * 8;

  f32x4 acc[4][4] = {};

  for (int kt = 0; kt < klimit; kt += 32) {
#pragma unroll
    for (int c = 0; c < 2; c++) {
      int r0 = wave * 32 + c * 16;
      gld16(Ag + (long)(r0 + srow) * Sn + kt + schunk, &As[r0 * 32]);
      gld16(Bg + (long)(r0 + srow) * Sn + kt + schunk, &Bs[r0 * 32]);
    }
    __syncthreads();

    bf16x8 af[4], bfrg[4];
#pragma unroll
    for (int t = 0; t < 4; t++)
      af[t] = *(const bf16x8*)&As[(waveM * 64 + t * 16 + l16) * 32 + quad * 8];
#pragma unroll
    for (int u = 0; u < 4; u++)
      bfrg[u] = *(const bf16x8*)&Bs[(waveN * 64 + u * 16 + l16) * 32 + quad * 8];
#pragma unroll
    for (int t = 0; t < 4; t++)
#pragma unroll
      for (int u = 0; u < 4; u++)
        acc[t][u] = __builtin_amdgcn_mfma_f32_16x16x32_bf16(af[t], bfrg[u],
                                                            acc[t][u], 0, 0, 0);
    __syncthreads();
  }

#pragma unroll
  for (int t = 0; t < 4; t++)
#pragma unroll
    for (int u = 0; u < 4; u++) {
      int col = colBase + waveN * 64 + u * 16 + l16;
#pragma unroll
      for (int r = 0; r < 4; r++) {
        long qAbs = (long)qBase + waveM * 64 + t * 16 + quad * 4 + r;
        stc(o + ((long)b * Sn + qAbs) * Hn + col, acc[t][u][r]);
      }
    }
}

// ---------------------------------------------------------------------------
// Softmax (vectorized bf16x8); zero-fills to 128-aligned limit for PV.
// ---------------------------------------------------------------------------
__global__ void __launch_bounds__(256) softmax_kernel(
    bf16* __restrict__ sc, const int* __restrict__ mask, int q0) {
  int qRel = blockIdx.x;
  int b = blockIdx.y;
  int qg = q0 + qRel;
  bf16* row = sc + ((long)b * CQ + qRel) * Sn;
  const int* mrow = mask + b * Sn;
  int tid = threadIdx.x;
  int n = qg + 1;
  int limit = (qg & ~127) + 128;
  int k0 = tid * 8;

  Pk8 pk;
  pk.v = *reinterpret_cast<const float4*>(row + k0);
  int4 m0 = *reinterpret_cast<const int4*>(mrow + k0);
  int4 m1 = *reinterpret_cast<const int4*>(mrow + k0 + 4);
  int mm[8] = {m0.x, m0.y, m0.z, m0.w, m1.x, m1.y, m1.z, m1.w};

  float sv[8];
  float lmax = -1e30f;
#pragma unroll
  for (int j = 0; j < 8; j++) {
    int kk = k0 + j;
    float s = (kk < n && mm[j] != 0) ? b2f(pk.h[j]) : -1e30f;
    sv[j] = s;
    lmax = fmaxf(lmax, s);
  }
  __shared__ float sb[4];
  __shared__ float stat;
#pragma unroll
  for (int off = 32; off > 0; off >>= 1)
    lmax = fmaxf(lmax, __shfl_down(lmax, off, 64));
  if ((tid & 63) == 0) sb[tid >> 6] = lmax;
  __syncthreads();
  if (tid == 0) stat = fmaxf(fmaxf(sb[0], sb[1]), fmaxf(sb[2], sb[3]));
  __syncthreads();
  float gmax = stat;

  float ev[8];
  float lsum = 0.f;
#pragma unroll
  for (int j = 0; j < 8; j++) {
    float e = (sv[j] > -1e29f) ? __expf(sv[j] - gmax) : 0.f;
    ev[j] = e;
    lsum += e;
  }
#pragma unroll
  for (int off = 32; off > 0; off >>= 1) lsum += __shfl_down(lsum, off, 64);
  if ((tid & 63) == 0) sb[tid >> 6] = lsum;
  __syncthreads();
  if (tid == 0) stat = sb[0] + sb[1] + sb[2] + sb[3];
  __syncthreads();
  float inv = 1.0f / stat;

  if (k0 < limit) {
    Pk8 o;
#pragma unroll
    for (int j = 0; j < 8; j++)
      o.h[j] = __float2bfloat16((k0 + j < n) ? ev[j] * inv : 0.f);
    *reinterpret_cast<float4*>(row + k0) = o.v;
  }
}

// ---------------------------------------------------------------------------
// Classifier head
// ---------------------------------------------------------------------------
__global__ void __launch_bounds__(256) cls_kernel(
    const bf16* __restrict__ h, const int* __restrict__ mask,
    const float* __restrict__ clsW, const float* __restrict__ clsb,
    float* __restrict__ out) {
  int b = blockIdx.x;
  int tid = threadIdx.x;
  __shared__ float sb[4];
  __shared__ int ib[4];
  __shared__ int lastsh;

  int ls = 0;
  for (int s = tid; s < Sn; s += 256) ls += mask[b * Sn + s];
#pragma unroll
  for (int off = 32; off > 0; off >>= 1) ls += __shfl_down(ls, off, 64);
  if ((tid & 63) == 0) ib[tid >> 6] = ls;
  __syncthreads();
  if (tid == 0) lastsh = ib[0] + ib[1] + ib[2] + ib[3] - 1;
  __syncthreads();
  int last = lastsh;

  const bf16* row = h + ((long)b * Sn + last) * Hn;
  float acc = 0.f;
  for (int d = tid; d < Hn; d += 256) acc += b2f(row[d]) * clsW[d];
#pragma unroll
  for (int off = 32; off > 0; off >>= 1) acc += __shfl_down(acc, off, 64);
  if ((tid & 63) == 0) sb[tid >> 6] = acc;
  __syncthreads();
  if (tid == 0) out[b] = sb[0] + sb[1] + sb[2] + sb[3] + clsb[0];
}

// ---------------------------------------------------------------------------
// Orchestration
// ---------------------------------------------------------------------------
extern "C" void kernel_launch(void* const* d_in, const int* in_sizes, int n_in,
                              void* d_out, int out_size, void* d_ws,
                              size_t ws_size, hipStream_t stream) {
  const int* ids     = (const int*)d_in[0];
  const int* mask    = (const int*)d_in[1];
  const float* tok   = (const float*)d_in[2];
  const float* pos   = (const float*)d_in[3];
  const float* Wq    = (const float*)d_in[4];
  const float* bq    = (const float*)d_in[5];
  const float* Wk    = (const float*)d_in[6];
  const float* bk    = (const float*)d_in[7];
  const float* Wv    = (const float*)d_in[8];
  const float* bv    = (const float*)d_in[9];
  const float* Wo    = (const float*)d_in[10];
  const float* bo    = (const float*)d_in[11];
  const float* ln1g  = (const float*)d_in[12];
  const float* ln1b  = (const float*)d_in[13];
  const float* ln2g  = (const float*)d_in[14];
  const float* ln2b  = (const float*)d_in[15];
  const float* W1    = (const float*)d_in[16];
  const float* b1    = (const float*)d_in[17];
  const float* W2    = (const float*)d_in[18];
  const float* b2    = (const float*)d_in[19];
  const float* flng  = (const float*)d_in[20];
  const float* flnb  = (const float*)d_in[21];
  const float* clsW  = (const float*)d_in[22];
  const float* clsb  = (const float*)d_in[23];

  float* x = (float*)d_ws;
  bf16* h  = (bf16*)(x + (size_t)BSn * Hn);
  bf16* cb = h + (size_t)BSn * Hn;
  bf16* qb = cb;                          // [BSn][Hn]
  bf16* kb = cb + (size_t)BSn * Hn;       // [BSn][Hn]
  bf16* vtb = cb + 2 * (size_t)BSn * Hn;  // V^T [Bn][Hn][Sn]
  bf16* scb = cb + 3 * (size_t)BSn * Hn;  // [Bn, CQ, Sn]
  bf16* wt = cb + (size_t)BSn * FFn;
  bf16* wqT = wt;                                   // wq,wk,wv contiguous
  bf16* woT = wqT + 3 * (size_t)Hn * Hn;
  bf16* w1T = woT + (size_t)Hn * Hn;                // [FF][H]
  bf16* w2T = w1T + (size_t)Hn * FFn;               // [H][FF]

  const int M = BSn;
  dim3 blk(256);
  dim3 blk512(512);
  dim3 gridQK(Sn / 128, CQ / 128, Bn);
  dim3 gridSM(CQ, Bn);
  dim3 gridPV(Hn / 128, CQ / 128, Bn);

  embed_kernel<<<BSn, blk, 0, stream>>>(ids, tok, pos, x);

  for (int l = 0; l < Ln; l++) {
    const float* Wq_l = Wq + (size_t)l * Hn * Hn;
    const float* Wk_l = Wk + (size_t)l * Hn * Hn;
    const float* Wv_l = Wv + (size_t)l * Hn * Hn;
    const float* Wo_l = Wo + (size_t)l * Hn * Hn;
    const float* W1_l = W1 + (size_t)l * Hn * FFn;
    const float* W2_l = W2 + (size_t)l * FFn * Hn;

    transpose_all_kernel<<<6912, blk, 0, stream>>>(Wq_l, Wk_l, Wv_l, Wo_l,
                                                   W1_l, W2_l, wt);

    // --- attention block ---
    ln_kernel<<<BSn, blk, 0, stream>>>(x, ln1g + l * Hn, ln1b + l * Hn, h);
    // fused QKV (M=16384, N=2304, K=768): 576 blocks
    gemm256_kernel<4, bf16><<<576, blk512, 0, stream>>>(
        h, wqT, bq + l * Hn, nullptr, qb, M, 3 * Hn, Hn,
        bk + l * Hn, bv + l * Hn);
    for (int c = 0; c < Sn / CQ; c++) {
      int q0 = c * CQ;
      qk_mfma_kernel<<<gridQK, blk, 0, stream>>>(qb, kb, scb, q0);
      softmax_kernel<<<gridSM, blk, 0, stream>>>(scb, mask, q0);
      pv_mfma_kernel<<<gridPV, blk, 0, stream>>>(scb, vtb, h, q0);
    }
    // Wo (N=768, K=768): 192 blocks
    gemm256_kernel<1, float><<<192, blk512, 0, stream>>>(
        h, woT, bo + l * Hn, x, x, M, Hn, Hn, nullptr, nullptr);

    // --- FFN block ---
    ln_kernel<<<BSn, blk, 0, stream>>>(x, ln2g + l * Hn, ln2b + l * Hn, h);
    // W1 (N=3072, K=768): 768 blocks
    gemm256_kernel<2, bf16><<<768, blk512, 0, stream>>>(
        h, w1T, b1 + l * FFn, nullptr, cb, M, FFn, Hn, nullptr, nullptr);
    // W2 (N=768, K=3072): 192 blocks
    gemm256_kernel<1, float><<<192, blk512, 0, stream>>>(
        cb, w2T, b2 + l * Hn, x, x, M, Hn, FFn, nullptr, nullptr);
  }

  ln_kernel<<<BSn, blk, 0, stream>>>(x, flng, flnb, h);
  cls_kernel<<<Bn, blk, 0, stream>>>(h, mask, clsW, clsb, (float*)d_out);
}